// Round 2
// baseline (277.716 us; speedup 1.0000x reference)
//
#include <hip/hip_runtime.h>

// ---------------- workspace layout (indices into uint32/float32 view) -------
// wsu[0] = min key, wsu[1] = max key (monotonic uint mapping of float)
// wsu[2..257]   = hist[256]
// wsf[258..514] = edges[257]
// wsf[515] = vmin, wsf[516] = delta, wsf[517] = inv_delta, wsf[518] = thresh
// byte offset 4096: gray[npix] (if ws_size permits)
static constexpr int HIST_OFF   = 2;
static constexpr int EDGES_OFF  = 258;
static constexpr int VMIN_OFF   = 515;
static constexpr int DELTA_OFF  = 516;
static constexpr int INVD_OFF   = 517;
static constexpr int THRESH_OFF = 518;
static constexpr size_t GRAY_BYTE_OFF = 4096;

typedef float nfloat4 __attribute__((ext_vector_type(4)));

__device__ __forceinline__ unsigned fkey(float x) {
    unsigned u = __float_as_uint(x);
    return (u & 0x80000000u) ? ~u : (u | 0x80000000u);
}
__device__ __forceinline__ float keyf(unsigned k) {
    return (k & 0x80000000u) ? __uint_as_float(k & 0x7FFFFFFFu)
                             : __uint_as_float(~k);
}
// gray = ((r*wr + g*wg) + b*wb), strict f32 rounding, NO fma contraction
__device__ __forceinline__ float gray1(float r, float g, float b) {
    float t0 = __fmul_rn(r, 0.2989f);
    float t1 = __fmul_rn(g, 0.5870f);
    float t2 = __fmul_rn(b, 0.1140f);
    return __fadd_rn(__fadd_rn(t0, t1), t2);
}

__global__ void init_kernel(unsigned* __restrict__ wsu) {
    int i = threadIdx.x;
    if (i < 256) wsu[HIST_OFF + i] = 0u;
    if (i == 0) { wsu[0] = 0xFFFFFFFFu; wsu[1] = 0u; }
}

// ---------- gray pass: staged LDS double-buffer, pinned prefetch ------------
// R8 history: (a) global_load_lds DMA version: 65.8 us -- hipcc drains the
// DMA queue with vmcnt(0) before any aliasing ds_read, prefetch depth 0.
// (b) register-streaming version: 60 us, VGPR_Count=28 proves the compiler
// SANK the 12 "independent" loads to their uses (48 VGPRs would be needed to
// hold them), serializing the stream. Both ran ~2 TB/s with VALUBusy 4%.
// This version forces the pipeline structurally: unit-stride loads into named
// regs, sched_barrier(0) pins them at their issue point (no sinking), LDS
// wave-private double buffer does the 48-B-stride transpose. ds_read_b128 at
// 48-B lane stride touches all 32 banks exactly once per 8-lane phase ->
// conflict-free (matches ~0 SQ_LDS_BANK_CONFLICT in both prior versions).
// Requires npix4 % 1024 == 0.
__global__ void __launch_bounds__(256)
gray_minmax_lds(const float* __restrict__ in, float* __restrict__ gray,
                unsigned* __restrict__ wsu, int npix4) {
    __shared__ float4 sb[4][2][192];              // 4 waves x 2 bufs x 3 KB
    __shared__ unsigned smn[4], smx[4];
    const float4* __restrict__ in4 = (const float4*)in;
    float4* __restrict__ gray4 = (float4*)gray;
    const int lane = threadIdx.x & 63;
    const int w = threadIdx.x >> 6;
    const int gw = blockIdx.x * 4 + w;            // global wave id
    const size_t base = (size_t)gw * 768;         // wave's first input float4
    unsigned mn = 0xFFFFFFFFu, mx = 0u;

    // prologue: tile0 -> regs -> buf0; tile1 -> regs (stays in flight)
    float4 a0 = in4[base + lane];
    float4 a1 = in4[base + 64 + lane];
    float4 a2 = in4[base + 128 + lane];
    __builtin_amdgcn_sched_barrier(0);
    sb[w][0][lane]       = a0;
    sb[w][0][64 + lane]  = a1;
    sb[w][0][128 + lane] = a2;
    a0 = in4[base + 192 + lane];
    a1 = in4[base + 256 + lane];
    a2 = in4[base + 320 + lane];
    __builtin_amdgcn_sched_barrier(0);

#pragma unroll
    for (int t = 0; t < 4; ++t) {
        const int cb = t & 1;
        // consume current tile (transpose read: lane gets 3 consecutive f4)
        float4 c0 = sb[w][cb][3 * lane + 0];
        float4 c1 = sb[w][cb][3 * lane + 1];
        float4 c2 = sb[w][cb][3 * lane + 2];
        float g0 = gray1(c0.x, c0.y, c0.z);
        float g1 = gray1(c0.w, c1.x, c1.y);
        float g2 = gray1(c1.z, c1.w, c2.x);
        float g3 = gray1(c2.y, c2.z, c2.w);
        gray4[(size_t)gw * 256 + t * 64 + lane] = make_float4(g0, g1, g2, g3);
        unsigned k0 = fkey(g0), k1 = fkey(g1), k2 = fkey(g2), k3 = fkey(g3);
        mn = min(mn, min(min(k0, k1), min(k2, k3)));
        mx = max(mx, max(max(k0, k1), max(k2, k3)));
        if (t < 3) {
            // stage tile t+1 (regs -> other buffer), then prefetch tile t+2
            sb[w][cb ^ 1][lane]       = a0;
            sb[w][cb ^ 1][64 + lane]  = a1;
            sb[w][cb ^ 1][128 + lane] = a2;
            if (t < 2) {
                a0 = in4[base + (size_t)(t + 2) * 192 + lane];
                a1 = in4[base + (size_t)(t + 2) * 192 + 64 + lane];
                a2 = in4[base + (size_t)(t + 2) * 192 + 128 + lane];
            }
            __builtin_amdgcn_sched_barrier(0);
        }
    }
    for (int off = 32; off > 0; off >>= 1) {
        mn = min(mn, (unsigned)__shfl_xor((int)mn, off, 64));
        mx = max(mx, (unsigned)__shfl_xor((int)mx, off, 64));
    }
    if (lane == 0) { smn[w] = mn; smx[w] = mx; }
    __syncthreads();
    if (threadIdx.x == 0) {
        mn = min(min(smn[0], smn[1]), min(smn[2], smn[3]));
        mx = max(max(smx[0], smx[1]), max(smx[2], smx[3]));
        atomicMin(&wsu[0], mn);
        atomicMax(&wsu[1], mx);
    }
}

// generic fallback (R2 shape, proven correct for any size)
__global__ void __launch_bounds__(256)
gray_minmax_generic(const float* __restrict__ in, float* __restrict__ gray,
                    unsigned* __restrict__ wsu, int npix4) {
    __shared__ unsigned smn[4], smx[4];
    const float4* in4 = (const float4*)in;
    const int stride = gridDim.x * blockDim.x;
    unsigned mn = 0xFFFFFFFFu, mx = 0u;
    for (int t = blockIdx.x * blockDim.x + threadIdx.x; t < npix4; t += stride) {
        const float4* p = in4 + (size_t)t * 3;
        float4 c0 = p[0], c1 = p[1], c2 = p[2];
        float g0 = gray1(c0.x, c0.y, c0.z);
        float g1 = gray1(c0.w, c1.x, c1.y);
        float g2 = gray1(c1.z, c1.w, c2.x);
        float g3 = gray1(c2.y, c2.z, c2.w);
        if (gray) ((float4*)gray)[t] = make_float4(g0, g1, g2, g3);
        unsigned k0 = fkey(g0), k1 = fkey(g1), k2 = fkey(g2), k3 = fkey(g3);
        mn = min(mn, min(min(k0, k1), min(k2, k3)));
        mx = max(mx, max(max(k0, k1), max(k2, k3)));
    }
    for (int off = 32; off > 0; off >>= 1) {
        mn = min(mn, (unsigned)__shfl_xor((int)mn, off, 64));
        mx = max(mx, (unsigned)__shfl_xor((int)mx, off, 64));
    }
    int wave = threadIdx.x >> 6;
    if ((threadIdx.x & 63) == 0) { smn[wave] = mn; smx[wave] = mx; }
    __syncthreads();
    if (threadIdx.x == 0) {
        mn = min(min(smn[0], smn[1]), min(smn[2], smn[3]));
        mx = max(max(smx[0], smx[1]), max(smx[2], smx[3]));
        atomicMin(&wsu[0], mn);
        atomicMax(&wsu[1], mx);
    }
}

// replicate jnp.linspace(vmin, vmax, 257) in f32 (see R2-R6, absmax 0)
__global__ void edges_kernel(const unsigned* __restrict__ wsu,
                             float* __restrict__ wsf) {
    float vmin = keyf(wsu[0]);
    float vmax = keyf(wsu[1]);
    float delta = __fdiv_rn(__fsub_rn(vmax, vmin), 256.0f);
    int i = threadIdx.x;
    if (i <= 256) {
        float e = (i == 256) ? vmax
                             : __fadd_rn(vmin, __fmul_rn((float)i, delta));
        wsf[EDGES_OFF + i] = e;
    }
    if (i == 0) {
        wsf[VMIN_OFF]  = vmin;
        wsf[DELTA_OFF] = delta;
        wsf[INVD_OFF]  = (delta > 0.0f) ? __fdiv_rn(1.0f, delta) : 0.0f;
    }
}

__device__ __forceinline__ void bin4(float x0, float x1, float x2, float x3,
                                     const float* eds, float vmin, float invd,
                                     unsigned* lh) {
    float xs[4] = {x0, x1, x2, x3};
#pragma unroll
    for (int j = 0; j < 4; ++j) {
        float x = xs[j];
        int b = (int)(__fmul_rn(__fsub_rn(x, vmin), invd));
        b = b < 0 ? 0 : (b > 255 ? 255 : b);
        while (b < 255 && x >= eds[b + 1]) ++b;   // exact searchsorted fixup
        while (b > 0 && x < eds[b]) --b;
        atomicAdd(&lh[b], 1u);
    }
}

// 8 coalesced gray-float4 loads per thread; per-block LDS hist, one global
// atomicAdd per bin per block.
__global__ void __launch_bounds__(256)
hist_kernel(const float* __restrict__ gray, const float* __restrict__ in,
            const float* __restrict__ wsf, unsigned* __restrict__ wsu,
            int npix4) {
    __shared__ float eds[257];
    __shared__ unsigned lh[256];
    for (int i = threadIdx.x; i < 257; i += blockDim.x)
        eds[i] = wsf[EDGES_OFF + i];
    if (threadIdx.x < 256) lh[threadIdx.x] = 0u;
    __syncthreads();
    const float vmin = eds[0];
    const float invd = wsf[INVD_OFF];
    const int stride = gridDim.x * blockDim.x;
    const int base = blockIdx.x * blockDim.x + threadIdx.x;
    if (gray && base + 7 * stride < npix4) {
        float4 g[8];
#pragma unroll
        for (int j = 0; j < 8; ++j) g[j] = ((const float4*)gray)[base + j * stride];
#pragma unroll
        for (int j = 0; j < 8; ++j)
            bin4(g[j].x, g[j].y, g[j].z, g[j].w, eds, vmin, invd, lh);
    } else {
        for (int t = base; t < npix4; t += stride) {
            float4 g4;
            if (gray) g4 = ((const float4*)gray)[t];
            else {
                const float4* p = (const float4*)in + (size_t)t * 3;
                float4 c0 = p[0], c1 = p[1], c2 = p[2];
                g4 = make_float4(gray1(c0.x, c0.y, c0.z), gray1(c0.w, c1.x, c1.y),
                                 gray1(c1.z, c1.w, c2.x), gray1(c2.y, c2.z, c2.w));
            }
            bin4(g4.x, g4.y, g4.z, g4.w, eds, vmin, invd, lh);
        }
    }
    __syncthreads();
    if (threadIdx.x < 256 && lh[threadIdx.x] != 0u)
        atomicAdd(&wsu[HIST_OFF + threadIdx.x], lh[threadIdx.x]);
}

// sequential f32 Otsu scan on one thread (order-faithful to numpy cumsum)
__global__ void otsu_kernel(const unsigned* __restrict__ wsu,
                            float* __restrict__ wsf) {
    __shared__ float histf[256];
    __shared__ float centers[256];
    __shared__ float w2a[256];
    __shared__ float s2a[256];
    int i = threadIdx.x;
    float e0 = wsf[EDGES_OFF + i];
    float e1 = wsf[EDGES_OFF + i + 1];
    centers[i] = __fmul_rn(__fadd_rn(e0, e1), 0.5f);
    histf[i] = (float)wsu[HIST_OFF + i];
    __syncthreads();
    if (i == 0) {
        float w = 0.0f, s = 0.0f;
        for (int t = 255; t >= 0; --t) {
            w = __fadd_rn(w, histf[t]);
            s = __fadd_rn(s, __fmul_rn(histf[t], centers[t]));
            w2a[t] = w;
            s2a[t] = s;
        }
        float w1 = 0.0f, s1 = 0.0f, best = -1.0f;
        int bidx = 0;
        for (int t = 0; t < 255; ++t) {
            w1 = __fadd_rn(w1, histf[t]);
            s1 = __fadd_rn(s1, __fmul_rn(histf[t], centers[t]));
            float m1 = __fdiv_rn(s1, fmaxf(w1, 1.0f));
            float m2 = __fdiv_rn(s2a[t + 1], fmaxf(w2a[t + 1], 1.0f));
            float d  = __fsub_rn(m1, m2);
            float v  = __fmul_rn(__fmul_rn(w1, w2a[t + 1]), __fmul_rn(d, d));
            if (v > best) { best = v; bidx = t; }  // first max, like argmax
        }
        wsf[THRESH_OFF] = centers[bidx];
    }
}

// binarize: coalesced gray loads, bpermute expand, unit-stride full-line NT
// stores (R6; removed the 2x HBM write amplification)
__global__ void __launch_bounds__(256)
binarize_fast(const float* __restrict__ gray, const float* __restrict__ wsf,
              float* __restrict__ out, int npix4) {
    const float thr = wsf[THRESH_OFF];
    const nfloat4* gray4 = (const nfloat4*)gray;
    nfloat4* out4 = (nfloat4*)out;
    const int lane = threadIdx.x & 63;
    const int gw = (blockIdx.x * blockDim.x + threadIdx.x) >> 6;
    const int ma = lane / 3,         qa = lane % 3;
    const int mb = (64 + lane) / 3,  qb = (64 + lane) % 3;
    const int mc = (128 + lane) / 3, qc = (128 + lane) % 3;

    nfloat4 g[4];
    bool full[4];
#pragma unroll
    for (int r = 0; r < 4; ++r) {
        int gbase = gw * 256 + r * 64;
        full[r] = (gbase + 64 <= npix4);
        if (full[r]) g[r] = gray4[gbase + lane];
    }
#pragma unroll
    for (int r = 0; r < 4; ++r) {
        const int gbase = gw * 256 + r * 64;
        if (full[r]) {
            unsigned u = (g[r].x > thr ? 1u : 0u) |
                         (g[r].y > thr ? 0x100u : 0u) |
                         (g[r].z > thr ? 0x10000u : 0u) |
                         (g[r].w > thr ? 0x1000000u : 0u);
            const int rb = 3 * gbase;
#pragma unroll
            for (int k = 0; k < 3; ++k) {
                int m = (k == 0) ? ma : (k == 1) ? mb : mc;
                int q = (k == 0) ? qa : (k == 1) ? qb : qc;
                unsigned w = (unsigned)__builtin_amdgcn_ds_bpermute(4 * m,
                                                                    (int)u);
                float h0 = (w & 0xffu)       ? 1.0f : 0.0f;
                float h1 = (w & 0xff00u)     ? 1.0f : 0.0f;
                float h2 = (w & 0xff0000u)   ? 1.0f : 0.0f;
                float h3 = (w & 0xff000000u) ? 1.0f : 0.0f;
                nfloat4 o;
                o.x = (q == 0) ? h0 : (q == 1) ? h1 : h2;
                o.y = (q == 0) ? h0 : (q == 1) ? h1 : h3;
                o.z = (q == 0) ? h0 : (q == 1) ? h2 : h3;
                o.w = (q == 0) ? h1 : (q == 1) ? h2 : h3;
                __builtin_nontemporal_store(o, &out4[rb + 64 * k + lane]);
            }
        } else {
            int t = gbase + lane;
            if (t < npix4) {
                nfloat4 gg = gray4[t];
                float b0 = (gg.x > thr) ? 1.0f : 0.0f;
                float b1 = (gg.y > thr) ? 1.0f : 0.0f;
                float b2 = (gg.z > thr) ? 1.0f : 0.0f;
                float b3 = (gg.w > thr) ? 1.0f : 0.0f;
                nfloat4* o = out4 + (size_t)t * 3;
                __builtin_nontemporal_store((nfloat4){b0, b0, b0, b1}, &o[0]);
                __builtin_nontemporal_store((nfloat4){b1, b1, b2, b2}, &o[1]);
                __builtin_nontemporal_store((nfloat4){b2, b3, b3, b3}, &o[2]);
            }
        }
    }
}

__global__ void __launch_bounds__(256)
binarize_generic(const float* __restrict__ gray, const float* __restrict__ in,
                 const float* __restrict__ wsf, float* __restrict__ out,
                 int npix4) {
    const float thr = wsf[THRESH_OFF];
    const int stride = gridDim.x * blockDim.x;
    nfloat4* out4 = (nfloat4*)out;
    for (int t = blockIdx.x * blockDim.x + threadIdx.x; t < npix4; t += stride) {
        float4 g4;
        if (gray) g4 = ((const float4*)gray)[t];
        else {
            const float4* p = (const float4*)in + (size_t)t * 3;
            float4 c0 = p[0], c1 = p[1], c2 = p[2];
            g4 = make_float4(gray1(c0.x, c0.y, c0.z), gray1(c0.w, c1.x, c1.y),
                             gray1(c1.z, c1.w, c2.x), gray1(c2.y, c2.z, c2.w));
        }
        float b0 = (g4.x > thr) ? 1.0f : 0.0f;
        float b1 = (g4.y > thr) ? 1.0f : 0.0f;
        float b2 = (g4.z > thr) ? 1.0f : 0.0f;
        float b3 = (g4.w > thr) ? 1.0f : 0.0f;
        nfloat4* o = out4 + (size_t)t * 3;
        o[0] = (nfloat4){b0, b0, b0, b1};
        o[1] = (nfloat4){b1, b1, b2, b2};
        o[2] = (nfloat4){b2, b3, b3, b3};
    }
}

extern "C" void kernel_launch(void* const* d_in, const int* in_sizes, int n_in,
                              void* d_out, int out_size, void* d_ws,
                              size_t ws_size, hipStream_t stream) {
    const float* in = (const float*)d_in[0];
    float* out = (float*)d_out;
    int npix  = out_size / 3;
    int npix4 = npix / 4;
    unsigned* wsu = (unsigned*)d_ws;
    float* wsf = (float*)d_ws;
    size_t need = GRAY_BYTE_OFF + (size_t)npix * sizeof(float);
    float* gray = (ws_size >= need)
                      ? (float*)((char*)d_ws + GRAY_BYTE_OFF)
                      : nullptr;

    hipLaunchKernelGGL(init_kernel, dim3(1), dim3(256), 0, stream, wsu);
    if (gray && npix4 % 1024 == 0) {
        // staged LDS double-buffer gray: wave = 4 tiles x 256 px
        hipLaunchKernelGGL(gray_minmax_lds, dim3(npix4 / 1024), dim3(256), 0,
                           stream, in, gray, wsu, npix4);
    } else {
        hipLaunchKernelGGL(gray_minmax_generic, dim3(2048), dim3(256), 0,
                           stream, in, gray, wsu, npix4);
    }
    hipLaunchKernelGGL(edges_kernel, dim3(1), dim3(320), 0, stream, wsu, wsf);
    hipLaunchKernelGGL(hist_kernel, dim3(1024), dim3(256), 0, stream,
                       gray, in, wsf, wsu, npix4);
    hipLaunchKernelGGL(otsu_kernel, dim3(1), dim3(256), 0, stream, wsu, wsf);
    if (gray) {
        hipLaunchKernelGGL(binarize_fast, dim3((npix4 + 1023) / 1024),
                           dim3(256), 0, stream, gray, wsf, out, npix4);
    } else {
        hipLaunchKernelGGL(binarize_generic, dim3(2048), dim3(256), 0, stream,
                           gray, in, wsf, out, npix4);
    }
}

// Round 3
// 259.320 us; speedup vs baseline: 1.0709x; 1.0709x over previous
//
#include <hip/hip_runtime.h>

// ---------------- workspace layout (indices into uint32/float32 view) -------
// wsu[0] = min key, wsu[1] = max key (fallback/atomic path only)
// wsu[2..257]   = hist[256]
// wsf[258..514] = edges[257]
// wsf[515] = vmin, wsf[516] = delta, wsf[517] = inv_delta, wsf[518] = thresh
// wsu[1024 .. 1024+2*nblk) = per-block (mn,mx) key pairs  (R9: atomic fix)
// byte offset 32768: gray[npix] (if ws_size permits)
static constexpr int HIST_OFF    = 2;
static constexpr int EDGES_OFF   = 258;
static constexpr int VMIN_OFF    = 515;
static constexpr int DELTA_OFF   = 516;
static constexpr int INVD_OFF    = 517;
static constexpr int THRESH_OFF  = 518;
static constexpr int SCRATCH_OFF = 1024;         // per-block minmax pairs
static constexpr size_t GRAY_BYTE_OFF = 32768;

typedef float nfloat4 __attribute__((ext_vector_type(4)));

__device__ __forceinline__ unsigned fkey(float x) {
    unsigned u = __float_as_uint(x);
    return (u & 0x80000000u) ? ~u : (u | 0x80000000u);
}
__device__ __forceinline__ float keyf(unsigned k) {
    return (k & 0x80000000u) ? __uint_as_float(k & 0x7FFFFFFFu)
                             : __uint_as_float(~k);
}
// gray = ((r*wr + g*wg) + b*wb), strict f32 rounding, NO fma contraction
__device__ __forceinline__ float gray1(float r, float g, float b) {
    float t0 = __fmul_rn(r, 0.2989f);
    float t1 = __fmul_rn(g, 0.5870f);
    float t2 = __fmul_rn(b, 0.1140f);
    return __fadd_rn(__fadd_rn(t0, t1), t2);
}

__global__ void init_kernel(unsigned* __restrict__ wsu) {
    int i = threadIdx.x;
    if (i < 256) wsu[HIST_OFF + i] = 0u;
    if (i == 0) { wsu[0] = 0xFFFFFFFFu; wsu[1] = 0u; }
}

// ---------- gray pass: staged LDS double-buffer -----------------------------
// R9 theory: R0(DMA)/R1(reg)/R2(LDS-staged) all ran 60-66 us at ~2.2 TB/s,
// VALUBusy 4%, Occupancy 39-44% -- runtime invariant under load structure.
// The shared piece was the epilogue: 2048 blocks x 2 device-scope atomics to
// the SAME two words. Same-address RMW serializes at the cross-XCD coherence
// point (~4096 ops). Occupancy decay (waves 1-3 exit, wave 0 parks on the
// atomic -> time-avg ~40%) matched exactly. Fix: plain-store each block's
// (mn,mx) pair to a private scratch slot; edges_kernel reduces 2048 pairs.
// Load/compute structure kept identical to R2 to isolate the variable.
// Requires npix4 % 1024 == 0.
__global__ void __launch_bounds__(256)
gray_minmax_lds(const float* __restrict__ in, float* __restrict__ gray,
                unsigned* __restrict__ wsu, int npix4) {
    __shared__ float4 sb[4][2][192];              // 4 waves x 2 bufs x 3 KB
    __shared__ unsigned smn[4], smx[4];
    const float4* __restrict__ in4 = (const float4*)in;
    float4* __restrict__ gray4 = (float4*)gray;
    const int lane = threadIdx.x & 63;
    const int w = threadIdx.x >> 6;
    const int gw = blockIdx.x * 4 + w;            // global wave id
    const size_t base = (size_t)gw * 768;         // wave's first input float4
    unsigned mn = 0xFFFFFFFFu, mx = 0u;

    // prologue: tile0 -> regs -> buf0; tile1 -> regs (stays in flight)
    float4 a0 = in4[base + lane];
    float4 a1 = in4[base + 64 + lane];
    float4 a2 = in4[base + 128 + lane];
    __builtin_amdgcn_sched_barrier(0);
    sb[w][0][lane]       = a0;
    sb[w][0][64 + lane]  = a1;
    sb[w][0][128 + lane] = a2;
    a0 = in4[base + 192 + lane];
    a1 = in4[base + 256 + lane];
    a2 = in4[base + 320 + lane];
    __builtin_amdgcn_sched_barrier(0);

#pragma unroll
    for (int t = 0; t < 4; ++t) {
        const int cb = t & 1;
        // consume current tile (transpose read: lane gets 3 consecutive f4)
        float4 c0 = sb[w][cb][3 * lane + 0];
        float4 c1 = sb[w][cb][3 * lane + 1];
        float4 c2 = sb[w][cb][3 * lane + 2];
        float g0 = gray1(c0.x, c0.y, c0.z);
        float g1 = gray1(c0.w, c1.x, c1.y);
        float g2 = gray1(c1.z, c1.w, c2.x);
        float g3 = gray1(c2.y, c2.z, c2.w);
        gray4[(size_t)gw * 256 + t * 64 + lane] = make_float4(g0, g1, g2, g3);
        unsigned k0 = fkey(g0), k1 = fkey(g1), k2 = fkey(g2), k3 = fkey(g3);
        mn = min(mn, min(min(k0, k1), min(k2, k3)));
        mx = max(mx, max(max(k0, k1), max(k2, k3)));
        if (t < 3) {
            // stage tile t+1 (regs -> other buffer), then prefetch tile t+2
            sb[w][cb ^ 1][lane]       = a0;
            sb[w][cb ^ 1][64 + lane]  = a1;
            sb[w][cb ^ 1][128 + lane] = a2;
            if (t < 2) {
                a0 = in4[base + (size_t)(t + 2) * 192 + lane];
                a1 = in4[base + (size_t)(t + 2) * 192 + 64 + lane];
                a2 = in4[base + (size_t)(t + 2) * 192 + 128 + lane];
            }
            __builtin_amdgcn_sched_barrier(0);
        }
    }
    for (int off = 32; off > 0; off >>= 1) {
        mn = min(mn, (unsigned)__shfl_xor((int)mn, off, 64));
        mx = max(mx, (unsigned)__shfl_xor((int)mx, off, 64));
    }
    if (lane == 0) { smn[w] = mn; smx[w] = mx; }
    __syncthreads();
    if (threadIdx.x == 0) {
        mn = min(min(smn[0], smn[1]), min(smn[2], smn[3]));
        mx = max(max(smx[0], smx[1]), max(smx[2], smx[3]));
        // R9: plain stores to a private slot -- NO same-address atomics
        wsu[SCRATCH_OFF + 2 * blockIdx.x]     = mn;
        wsu[SCRATCH_OFF + 2 * blockIdx.x + 1] = mx;
    }
}

// generic fallback (R2 shape, proven correct for any size; atomic path kept)
__global__ void __launch_bounds__(256)
gray_minmax_generic(const float* __restrict__ in, float* __restrict__ gray,
                    unsigned* __restrict__ wsu, int npix4) {
    __shared__ unsigned smn[4], smx[4];
    const float4* in4 = (const float4*)in;
    const int stride = gridDim.x * blockDim.x;
    unsigned mn = 0xFFFFFFFFu, mx = 0u;
    for (int t = blockIdx.x * blockDim.x + threadIdx.x; t < npix4; t += stride) {
        const float4* p = in4 + (size_t)t * 3;
        float4 c0 = p[0], c1 = p[1], c2 = p[2];
        float g0 = gray1(c0.x, c0.y, c0.z);
        float g1 = gray1(c0.w, c1.x, c1.y);
        float g2 = gray1(c1.z, c1.w, c2.x);
        float g3 = gray1(c2.y, c2.z, c2.w);
        if (gray) ((float4*)gray)[t] = make_float4(g0, g1, g2, g3);
        unsigned k0 = fkey(g0), k1 = fkey(g1), k2 = fkey(g2), k3 = fkey(g3);
        mn = min(mn, min(min(k0, k1), min(k2, k3)));
        mx = max(mx, max(max(k0, k1), max(k2, k3)));
    }
    for (int off = 32; off > 0; off >>= 1) {
        mn = min(mn, (unsigned)__shfl_xor((int)mn, off, 64));
        mx = max(mx, (unsigned)__shfl_xor((int)mx, off, 64));
    }
    int wave = threadIdx.x >> 6;
    if ((threadIdx.x & 63) == 0) { smn[wave] = mn; smx[wave] = mx; }
    __syncthreads();
    if (threadIdx.x == 0) {
        mn = min(min(smn[0], smn[1]), min(smn[2], smn[3]));
        mx = max(max(smx[0], smx[1]), max(smx[2], smx[3]));
        atomicMin(&wsu[0], mn);
        atomicMax(&wsu[1], mx);
    }
}

// R9: edges_kernel now also reduces the per-block (mn,mx) scratch pairs
// (nblk>0). nblk==0 -> read the atomic-produced wsu[0/1] (fallback path).
// Edge values bit-identical to previous rounds (absmax 0 preserved):
// e_i = fadd(vmin, fmul(i, delta)) for i<256, e_256 = vmax.
__global__ void edges_kernel(unsigned* __restrict__ wsu,
                             float* __restrict__ wsf, int nblk) {
    __shared__ unsigned rmn[4], rmx[4];
    const int i = threadIdx.x;                    // 0..255
    unsigned mn = 0xFFFFFFFFu, mx = 0u;
    if (nblk > 0) {
        for (int b = i; b < nblk; b += 256) {
            mn = min(mn, wsu[SCRATCH_OFF + 2 * b]);
            mx = max(mx, wsu[SCRATCH_OFF + 2 * b + 1]);
        }
        for (int off = 32; off > 0; off >>= 1) {
            mn = min(mn, (unsigned)__shfl_xor((int)mn, off, 64));
            mx = max(mx, (unsigned)__shfl_xor((int)mx, off, 64));
        }
        const int w = i >> 6;
        if ((i & 63) == 0) { rmn[w] = mn; rmx[w] = mx; }
        __syncthreads();
        mn = min(min(rmn[0], rmn[1]), min(rmn[2], rmn[3]));
        mx = max(max(rmx[0], rmx[1]), max(rmx[2], rmx[3]));
    } else {
        mn = wsu[0];
        mx = wsu[1];
    }
    const float vmin = keyf(mn);
    const float vmax = keyf(mx);
    const float delta = __fdiv_rn(__fsub_rn(vmax, vmin), 256.0f);
    wsf[EDGES_OFF + i] = __fadd_rn(vmin, __fmul_rn((float)i, delta));
    if (i == 0) {
        wsf[EDGES_OFF + 256] = vmax;
        wsf[VMIN_OFF]  = vmin;
        wsf[DELTA_OFF] = delta;
        wsf[INVD_OFF]  = (delta > 0.0f) ? __fdiv_rn(1.0f, delta) : 0.0f;
    }
}

__device__ __forceinline__ void bin4(float x0, float x1, float x2, float x3,
                                     const float* eds, float vmin, float invd,
                                     unsigned* lh) {
    float xs[4] = {x0, x1, x2, x3};
#pragma unroll
    for (int j = 0; j < 4; ++j) {
        float x = xs[j];
        int b = (int)(__fmul_rn(__fsub_rn(x, vmin), invd));
        b = b < 0 ? 0 : (b > 255 ? 255 : b);
        while (b < 255 && x >= eds[b + 1]) ++b;   // exact searchsorted fixup
        while (b > 0 && x < eds[b]) --b;
        atomicAdd(&lh[b], 1u);
    }
}

// 8 coalesced gray-float4 loads per thread; per-block LDS hist, one global
// atomicAdd per bin per block (256 distinct addresses -> pipelined RMW).
__global__ void __launch_bounds__(256)
hist_kernel(const float* __restrict__ gray, const float* __restrict__ in,
            const float* __restrict__ wsf, unsigned* __restrict__ wsu,
            int npix4) {
    __shared__ float eds[257];
    __shared__ unsigned lh[256];
    for (int i = threadIdx.x; i < 257; i += blockDim.x)
        eds[i] = wsf[EDGES_OFF + i];
    if (threadIdx.x < 256) lh[threadIdx.x] = 0u;
    __syncthreads();
    const float vmin = eds[0];
    const float invd = wsf[INVD_OFF];
    const int stride = gridDim.x * blockDim.x;
    const int base = blockIdx.x * blockDim.x + threadIdx.x;
    if (gray && base + 7 * stride < npix4) {
        float4 g[8];
#pragma unroll
        for (int j = 0; j < 8; ++j) g[j] = ((const float4*)gray)[base + j * stride];
#pragma unroll
        for (int j = 0; j < 8; ++j)
            bin4(g[j].x, g[j].y, g[j].z, g[j].w, eds, vmin, invd, lh);
    } else {
        for (int t = base; t < npix4; t += stride) {
            float4 g4;
            if (gray) g4 = ((const float4*)gray)[t];
            else {
                const float4* p = (const float4*)in + (size_t)t * 3;
                float4 c0 = p[0], c1 = p[1], c2 = p[2];
                g4 = make_float4(gray1(c0.x, c0.y, c0.z), gray1(c0.w, c1.x, c1.y),
                                 gray1(c1.z, c1.w, c2.x), gray1(c2.y, c2.z, c2.w));
            }
            bin4(g4.x, g4.y, g4.z, g4.w, eds, vmin, invd, lh);
        }
    }
    __syncthreads();
    if (threadIdx.x < 256 && lh[threadIdx.x] != 0u)
        atomicAdd(&wsu[HIST_OFF + threadIdx.x], lh[threadIdx.x]);
}

// sequential f32 Otsu scan on one thread (order-faithful to numpy cumsum)
__global__ void otsu_kernel(const unsigned* __restrict__ wsu,
                            float* __restrict__ wsf) {
    __shared__ float histf[256];
    __shared__ float centers[256];
    __shared__ float w2a[256];
    __shared__ float s2a[256];
    int i = threadIdx.x;
    float e0 = wsf[EDGES_OFF + i];
    float e1 = wsf[EDGES_OFF + i + 1];
    centers[i] = __fmul_rn(__fadd_rn(e0, e1), 0.5f);
    histf[i] = (float)wsu[HIST_OFF + i];
    __syncthreads();
    if (i == 0) {
        float w = 0.0f, s = 0.0f;
        for (int t = 255; t >= 0; --t) {
            w = __fadd_rn(w, histf[t]);
            s = __fadd_rn(s, __fmul_rn(histf[t], centers[t]));
            w2a[t] = w;
            s2a[t] = s;
        }
        float w1 = 0.0f, s1 = 0.0f, best = -1.0f;
        int bidx = 0;
        for (int t = 0; t < 255; ++t) {
            w1 = __fadd_rn(w1, histf[t]);
            s1 = __fadd_rn(s1, __fmul_rn(histf[t], centers[t]));
            float m1 = __fdiv_rn(s1, fmaxf(w1, 1.0f));
            float m2 = __fdiv_rn(s2a[t + 1], fmaxf(w2a[t + 1], 1.0f));
            float d  = __fsub_rn(m1, m2);
            float v  = __fmul_rn(__fmul_rn(w1, w2a[t + 1]), __fmul_rn(d, d));
            if (v > best) { best = v; bidx = t; }  // first max, like argmax
        }
        wsf[THRESH_OFF] = centers[bidx];
    }
}

// binarize: coalesced gray loads, bpermute expand, unit-stride full-line NT
// stores (R6; removed the 2x HBM write amplification)
__global__ void __launch_bounds__(256)
binarize_fast(const float* __restrict__ gray, const float* __restrict__ wsf,
              float* __restrict__ out, int npix4) {
    const float thr = wsf[THRESH_OFF];
    const nfloat4* gray4 = (const nfloat4*)gray;
    nfloat4* out4 = (nfloat4*)out;
    const int lane = threadIdx.x & 63;
    const int gw = (blockIdx.x * blockDim.x + threadIdx.x) >> 6;
    const int ma = lane / 3,         qa = lane % 3;
    const int mb = (64 + lane) / 3,  qb = (64 + lane) % 3;
    const int mc = (128 + lane) / 3, qc = (128 + lane) % 3;

    nfloat4 g[4];
    bool full[4];
#pragma unroll
    for (int r = 0; r < 4; ++r) {
        int gbase = gw * 256 + r * 64;
        full[r] = (gbase + 64 <= npix4);
        if (full[r]) g[r] = gray4[gbase + lane];
    }
#pragma unroll
    for (int r = 0; r < 4; ++r) {
        const int gbase = gw * 256 + r * 64;
        if (full[r]) {
            unsigned u = (g[r].x > thr ? 1u : 0u) |
                         (g[r].y > thr ? 0x100u : 0u) |
                         (g[r].z > thr ? 0x10000u : 0u) |
                         (g[r].w > thr ? 0x1000000u : 0u);
            const int rb = 3 * gbase;
#pragma unroll
            for (int k = 0; k < 3; ++k) {
                int m = (k == 0) ? ma : (k == 1) ? mb : mc;
                int q = (k == 0) ? qa : (k == 1) ? qb : qc;
                unsigned w = (unsigned)__builtin_amdgcn_ds_bpermute(4 * m,
                                                                    (int)u);
                float h0 = (w & 0xffu)       ? 1.0f : 0.0f;
                float h1 = (w & 0xff00u)     ? 1.0f : 0.0f;
                float h2 = (w & 0xff0000u)   ? 1.0f : 0.0f;
                float h3 = (w & 0xff000000u) ? 1.0f : 0.0f;
                nfloat4 o;
                o.x = (q == 0) ? h0 : (q == 1) ? h1 : h2;
                o.y = (q == 0) ? h0 : (q == 1) ? h1 : h3;
                o.z = (q == 0) ? h0 : (q == 1) ? h2 : h3;
                o.w = (q == 0) ? h1 : (q == 1) ? h2 : h3;
                __builtin_nontemporal_store(o, &out4[rb + 64 * k + lane]);
            }
        } else {
            int t = gbase + lane;
            if (t < npix4) {
                nfloat4 gg = gray4[t];
                float b0 = (gg.x > thr) ? 1.0f : 0.0f;
                float b1 = (gg.y > thr) ? 1.0f : 0.0f;
                float b2 = (gg.z > thr) ? 1.0f : 0.0f;
                float b3 = (gg.w > thr) ? 1.0f : 0.0f;
                nfloat4* o = out4 + (size_t)t * 3;
                __builtin_nontemporal_store((nfloat4){b0, b0, b0, b1}, &o[0]);
                __builtin_nontemporal_store((nfloat4){b1, b1, b2, b2}, &o[1]);
                __builtin_nontemporal_store((nfloat4){b2, b3, b3, b3}, &o[2]);
            }
        }
    }
}

__global__ void __launch_bounds__(256)
binarize_generic(const float* __restrict__ gray, const float* __restrict__ in,
                 const float* __restrict__ wsf, float* __restrict__ out,
                 int npix4) {
    const float thr = wsf[THRESH_OFF];
    const int stride = gridDim.x * blockDim.x;
    nfloat4* out4 = (nfloat4*)out;
    for (int t = blockIdx.x * blockDim.x + threadIdx.x; t < npix4; t += stride) {
        float4 g4;
        if (gray) g4 = ((const float4*)gray)[t];
        else {
            const float4* p = (const float4*)in + (size_t)t * 3;
            float4 c0 = p[0], c1 = p[1], c2 = p[2];
            g4 = make_float4(gray1(c0.x, c0.y, c0.z), gray1(c0.w, c1.x, c1.y),
                             gray1(c1.z, c1.w, c2.x), gray1(c2.y, c2.z, c2.w));
        }
        float b0 = (g4.x > thr) ? 1.0f : 0.0f;
        float b1 = (g4.y > thr) ? 1.0f : 0.0f;
        float b2 = (g4.z > thr) ? 1.0f : 0.0f;
        float b3 = (g4.w > thr) ? 1.0f : 0.0f;
        nfloat4* o = out4 + (size_t)t * 3;
        o[0] = (nfloat4){b0, b0, b0, b1};
        o[1] = (nfloat4){b1, b1, b2, b2};
        o[2] = (nfloat4){b2, b3, b3, b3};
    }
}

extern "C" void kernel_launch(void* const* d_in, const int* in_sizes, int n_in,
                              void* d_out, int out_size, void* d_ws,
                              size_t ws_size, hipStream_t stream) {
    const float* in = (const float*)d_in[0];
    float* out = (float*)d_out;
    int npix  = out_size / 3;
    int npix4 = npix / 4;
    unsigned* wsu = (unsigned*)d_ws;
    float* wsf = (float*)d_ws;
    size_t need = GRAY_BYTE_OFF + (size_t)npix * sizeof(float);
    float* gray = (ws_size >= need)
                      ? (float*)((char*)d_ws + GRAY_BYTE_OFF)
                      : nullptr;

    hipLaunchKernelGGL(init_kernel, dim3(1), dim3(256), 0, stream, wsu);
    int nblk = 0;
    if (gray && npix4 % 1024 == 0) {
        nblk = npix4 / 1024;                      // per-block minmax pairs
        hipLaunchKernelGGL(gray_minmax_lds, dim3(nblk), dim3(256), 0,
                           stream, in, gray, wsu, npix4);
    } else {
        hipLaunchKernelGGL(gray_minmax_generic, dim3(2048), dim3(256), 0,
                           stream, in, gray, wsu, npix4);
    }
    hipLaunchKernelGGL(edges_kernel, dim3(1), dim3(256), 0, stream, wsu, wsf,
                       nblk);
    hipLaunchKernelGGL(hist_kernel, dim3(1024), dim3(256), 0, stream,
                       gray, in, wsf, wsu, npix4);
    hipLaunchKernelGGL(otsu_kernel, dim3(1), dim3(256), 0, stream, wsu, wsf);
    if (gray) {
        hipLaunchKernelGGL(binarize_fast, dim3((npix4 + 1023) / 1024),
                           dim3(256), 0, stream, gray, wsf, out, npix4);
    } else {
        hipLaunchKernelGGL(binarize_generic, dim3(2048), dim3(256), 0, stream,
                           gray, in, wsf, out, npix4);
    }
}

// Round 4
// 259.047 us; speedup vs baseline: 1.0721x; 1.0011x over previous
//
#include <hip/hip_runtime.h>
#include <hip/hip_cooperative_groups.h>

namespace cg = cooperative_groups;

// ---------------- workspace layout (indices into uint32/float32 view) -------
// wsu[0] = min key, wsu[1] = max key (fallback/atomic path only)
// wsu[2..257]   = hist[256]
// wsf[258..514] = edges[257]      (fallback path)
// wsf[515] = vmin, wsf[516] = delta, wsf[517] = inv_delta, wsf[518] = thresh
// wsu[1024 .. 1024+2*nblk) = per-block (mn,mx) key pairs
// byte offset 32768: gray[npix] (fallback path only)
static constexpr int HIST_OFF    = 2;
static constexpr int EDGES_OFF   = 258;
static constexpr int VMIN_OFF    = 515;
static constexpr int DELTA_OFF   = 516;
static constexpr int INVD_OFF    = 517;
static constexpr int THRESH_OFF  = 518;
static constexpr int SCRATCH_OFF = 1024;         // per-block minmax pairs
static constexpr size_t GRAY_BYTE_OFF = 32768;

typedef float nfloat4 __attribute__((ext_vector_type(4)));

__device__ __forceinline__ unsigned fkey(float x) {
    unsigned u = __float_as_uint(x);
    return (u & 0x80000000u) ? ~u : (u | 0x80000000u);
}
__device__ __forceinline__ float keyf(unsigned k) {
    return (k & 0x80000000u) ? __uint_as_float(k & 0x7FFFFFFFu)
                             : __uint_as_float(~k);
}
// gray = ((r*wr + g*wg) + b*wb), strict f32 rounding, NO fma contraction
__device__ __forceinline__ float gray1(float r, float g, float b) {
    float t0 = __fmul_rn(r, 0.2989f);
    float t1 = __fmul_rn(g, 0.5870f);
    float t2 = __fmul_rn(b, 0.1140f);
    return __fadd_rn(__fadd_rn(t0, t1), t2);
}

__device__ __forceinline__ void bin4(float x0, float x1, float x2, float x3,
                                     const float* eds, float vmin, float invd,
                                     unsigned* lh) {
    float xs[4] = {x0, x1, x2, x3};
#pragma unroll
    for (int j = 0; j < 4; ++j) {
        float x = xs[j];
        int b = (int)(__fmul_rn(__fsub_rn(x, vmin), invd));
        b = b < 0 ? 0 : (b > 255 ? 255 : b);
        while (b < 255 && x >= eds[b + 1]) ++b;   // exact searchsorted fixup
        while (b > 0 && x < eds[b]) --b;
        atomicAdd(&lh[b], 1u);
    }
}

// =============== R10: single fused cooperative kernel =======================
// R0-R3 established: every pass is latency/overhead-bound, not BW-bound
// (harness memset does 6.7 TB/s; our 6-dispatch pipeline totals 259 us for
// ~300 MB of ideal traffic = 48 us). The residual ~150 us lives in the 6
// launch boundaries (full pipeline drain each) and two serial single-block
// kernels. This kernel fuses everything:
//   P1 gray+minmax (gray stays in 32 VGPRs/thread -- 100 MB of traffic gone)
//   P2 per-block redundant minmax-reduce -> edges in LDS
//   P3 hist from regs -> LDS -> global atomicAdd (256 distinct addresses)
//   P4 per-block redundant Otsu: serial cumsums on thread 0 (order-faithful),
//      parallel divisions on 255 threads, first-max argmax reduce
//   P5 binarize from regs, bpermute expand, NT full-line stores
// Cross-block data moves ONLY via device-scope atomics (scratch pairs, hist);
// bulk data never crosses blocks -> no L2-coherence hazards (Guideline 16).
// Requires npix4 == nblk*2048 and all nblk blocks co-resident (checked on
// host via hipOccupancyMaxActiveBlocksPerMultiprocessor).
__global__ void __launch_bounds__(256, 4)
fused_otsu(const float* __restrict__ in, float* __restrict__ out,
           unsigned* __restrict__ wsu, float* __restrict__ wsf, int nblk) {
    __shared__ float eds[257];
    __shared__ unsigned lh[256];
    __shared__ float histf[256], centers[256];
    __shared__ float w1a[256], s1a[256], w2a[256], s2a[256];
    __shared__ unsigned rmn[4], rmx[4];
    __shared__ float rbv[4];
    __shared__ int rbi[4];
    __shared__ float sthresh;

    const int t = threadIdx.x;
    const int lane = t & 63;
    const int w = t >> 6;
    const int b = blockIdx.x;
    const float4* __restrict__ in4 = (const float4*)in;
    nfloat4* __restrict__ out4 = (nfloat4*)out;
    const int base0 = b * 2048;                   // block's first gray4 group

    // ---- P1: gray + minmax; keep gray in registers --------------------------
    nfloat4 g[8];
    unsigned mn = 0xFFFFFFFFu, mx = 0u;
#pragma unroll
    for (int r = 0; r < 8; ++r) {
        const int idx = base0 + r * 256 + t;
        const float4* p = in4 + 3 * (size_t)idx;
        float4 c0 = p[0], c1 = p[1], c2 = p[2];
        float g0 = gray1(c0.x, c0.y, c0.z);
        float g1 = gray1(c0.w, c1.x, c1.y);
        float g2 = gray1(c1.z, c1.w, c2.x);
        float g3 = gray1(c2.y, c2.z, c2.w);
        g[r].x = g0; g[r].y = g1; g[r].z = g2; g[r].w = g3;
        unsigned k0 = fkey(g0), k1 = fkey(g1), k2 = fkey(g2), k3 = fkey(g3);
        mn = min(mn, min(min(k0, k1), min(k2, k3)));
        mx = max(mx, max(max(k0, k1), max(k2, k3)));
    }
    // block 0 zeroes the global hist before grid sync #1 (ordered before all
    // hist atomicAdds, which happen after the sync)
    if (b == 0)
        __hip_atomic_store(&wsu[HIST_OFF + t], 0u, __ATOMIC_RELAXED,
                           __HIP_MEMORY_SCOPE_AGENT);
    for (int off = 32; off > 0; off >>= 1) {
        mn = min(mn, (unsigned)__shfl_xor((int)mn, off, 64));
        mx = max(mx, (unsigned)__shfl_xor((int)mx, off, 64));
    }
    if (lane == 0) { rmn[w] = mn; rmx[w] = mx; }
    __syncthreads();
    if (t == 0) {
        mn = min(min(rmn[0], rmn[1]), min(rmn[2], rmn[3]));
        mx = max(max(rmx[0], rmx[1]), max(rmx[2], rmx[3]));
        __hip_atomic_store(&wsu[SCRATCH_OFF + 2 * b], mn, __ATOMIC_RELAXED,
                           __HIP_MEMORY_SCOPE_AGENT);
        __hip_atomic_store(&wsu[SCRATCH_OFF + 2 * b + 1], mx, __ATOMIC_RELAXED,
                           __HIP_MEMORY_SCOPE_AGENT);
    }
    cg::this_grid().sync();

    // ---- P2: every block redundantly reduces all pairs -> edges in LDS ------
    mn = 0xFFFFFFFFu; mx = 0u;
    for (int i = t; i < nblk; i += 256) {
        mn = min(mn, __hip_atomic_load(&wsu[SCRATCH_OFF + 2 * i],
                                       __ATOMIC_RELAXED,
                                       __HIP_MEMORY_SCOPE_AGENT));
        mx = max(mx, __hip_atomic_load(&wsu[SCRATCH_OFF + 2 * i + 1],
                                       __ATOMIC_RELAXED,
                                       __HIP_MEMORY_SCOPE_AGENT));
    }
    for (int off = 32; off > 0; off >>= 1) {
        mn = min(mn, (unsigned)__shfl_xor((int)mn, off, 64));
        mx = max(mx, (unsigned)__shfl_xor((int)mx, off, 64));
    }
    if (lane == 0) { rmn[w] = mn; rmx[w] = mx; }
    __syncthreads();
    mn = min(min(rmn[0], rmn[1]), min(rmn[2], rmn[3]));
    mx = max(max(rmx[0], rmx[1]), max(rmx[2], rmx[3]));
    const float vmin = keyf(mn);
    const float vmax = keyf(mx);
    const float delta = __fdiv_rn(__fsub_rn(vmax, vmin), 256.0f);
    const float invd = (delta > 0.0f) ? __fdiv_rn(1.0f, delta) : 0.0f;
    eds[t] = __fadd_rn(vmin, __fmul_rn((float)t, delta));
    if (t == 0) eds[256] = vmax;
    lh[t] = 0u;
    __syncthreads();

    // ---- P3: hist from registers -------------------------------------------
#pragma unroll
    for (int r = 0; r < 8; ++r)
        bin4(g[r].x, g[r].y, g[r].z, g[r].w, eds, vmin, invd, lh);
    __syncthreads();
    if (lh[t] != 0u) atomicAdd(&wsu[HIST_OFF + t], lh[t]);
    cg::this_grid().sync();

    // ---- P4: per-block redundant Otsu ---------------------------------------
    histf[t] = (float)__hip_atomic_load(&wsu[HIST_OFF + t], __ATOMIC_RELAXED,
                                        __HIP_MEMORY_SCOPE_AGENT);
    centers[t] = __fmul_rn(__fadd_rn(eds[t], eds[t + 1]), 0.5f);
    __syncthreads();
    if (t == 0) {
        float ww = 0.0f, ss = 0.0f;
        for (int k = 255; k >= 0; --k) {           // backward cumsums (exact)
            ww = __fadd_rn(ww, histf[k]);
            ss = __fadd_rn(ss, __fmul_rn(histf[k], centers[k]));
            w2a[k] = ww;
            s2a[k] = ss;
        }
        ww = 0.0f; ss = 0.0f;
        for (int k = 0; k < 255; ++k) {            // forward cumsums (exact)
            ww = __fadd_rn(ww, histf[k]);
            ss = __fadd_rn(ss, __fmul_rn(histf[k], centers[k]));
            w1a[k] = ww;
            s1a[k] = ss;
        }
    }
    __syncthreads();
    float v = -1.0f;
    int ti = 256;
    if (t < 255) {                                 // parallel divisions
        float m1 = __fdiv_rn(s1a[t], fmaxf(w1a[t], 1.0f));
        float m2 = __fdiv_rn(s2a[t + 1], fmaxf(w2a[t + 1], 1.0f));
        float d  = __fsub_rn(m1, m2);
        v  = __fmul_rn(__fmul_rn(w1a[t], w2a[t + 1]), __fmul_rn(d, d));
        ti = t;
    }
    for (int off = 32; off > 0; off >>= 1) {       // first-max argmax reduce
        float ov = __shfl_xor(v, off, 64);
        int oi = __shfl_xor(ti, off, 64);
        if (ov > v || (ov == v && oi < ti)) { v = ov; ti = oi; }
    }
    if (lane == 0) { rbv[w] = v; rbi[w] = ti; }
    __syncthreads();
    if (t == 0) {
        float bv = rbv[0]; int bi = rbi[0];
        for (int k = 1; k < 4; ++k)
            if (rbv[k] > bv || (rbv[k] == bv && rbi[k] < bi)) {
                bv = rbv[k]; bi = rbi[k];
            }
        sthresh = centers[bi];
        if (b == 0) wsf[THRESH_OFF] = centers[bi];  // for inspection/debug
    }
    __syncthreads();
    const float thr = sthresh;

    // ---- P5: binarize from registers, bpermute expand, NT stores ------------
    const int ma = lane / 3,         qa = lane % 3;
    const int mb = (64 + lane) / 3,  qb = (64 + lane) % 3;
    const int mc = (128 + lane) / 3, qc = (128 + lane) % 3;
#pragma unroll
    for (int r = 0; r < 8; ++r) {
        unsigned u = (g[r].x > thr ? 1u : 0u) |
                     (g[r].y > thr ? 0x100u : 0u) |
                     (g[r].z > thr ? 0x10000u : 0u) |
                     (g[r].w > thr ? 0x1000000u : 0u);
        const int wavebase = base0 + r * 256 + w * 64;   // wave's 64 groups
        const size_t rb = 3 * (size_t)wavebase;
#pragma unroll
        for (int k = 0; k < 3; ++k) {
            int m = (k == 0) ? ma : (k == 1) ? mb : mc;
            int q = (k == 0) ? qa : (k == 1) ? qb : qc;
            unsigned x = (unsigned)__builtin_amdgcn_ds_bpermute(4 * m, (int)u);
            float h0 = (x & 0xffu)       ? 1.0f : 0.0f;
            float h1 = (x & 0xff00u)     ? 1.0f : 0.0f;
            float h2 = (x & 0xff0000u)   ? 1.0f : 0.0f;
            float h3 = (x & 0xff000000u) ? 1.0f : 0.0f;
            nfloat4 o;
            o.x = (q == 0) ? h0 : (q == 1) ? h1 : h2;
            o.y = (q == 0) ? h0 : (q == 1) ? h1 : h3;
            o.z = (q == 0) ? h0 : (q == 1) ? h2 : h3;
            o.w = (q == 0) ? h1 : (q == 1) ? h2 : h3;
            __builtin_nontemporal_store(o, &out4[rb + 64 * k + lane]);
        }
    }
}

// =============== fallback multi-kernel pipeline (R3, proven) ================

__global__ void init_kernel(unsigned* __restrict__ wsu) {
    int i = threadIdx.x;
    if (i < 256) wsu[HIST_OFF + i] = 0u;
    if (i == 0) { wsu[0] = 0xFFFFFFFFu; wsu[1] = 0u; }
}

__global__ void __launch_bounds__(256)
gray_minmax_lds(const float* __restrict__ in, float* __restrict__ gray,
                unsigned* __restrict__ wsu, int npix4) {
    __shared__ float4 sb[4][2][192];
    __shared__ unsigned smn[4], smx[4];
    const float4* __restrict__ in4 = (const float4*)in;
    float4* __restrict__ gray4 = (float4*)gray;
    const int lane = threadIdx.x & 63;
    const int w = threadIdx.x >> 6;
    const int gw = blockIdx.x * 4 + w;
    const size_t base = (size_t)gw * 768;
    unsigned mn = 0xFFFFFFFFu, mx = 0u;

    float4 a0 = in4[base + lane];
    float4 a1 = in4[base + 64 + lane];
    float4 a2 = in4[base + 128 + lane];
    __builtin_amdgcn_sched_barrier(0);
    sb[w][0][lane]       = a0;
    sb[w][0][64 + lane]  = a1;
    sb[w][0][128 + lane] = a2;
    a0 = in4[base + 192 + lane];
    a1 = in4[base + 256 + lane];
    a2 = in4[base + 320 + lane];
    __builtin_amdgcn_sched_barrier(0);

#pragma unroll
    for (int t = 0; t < 4; ++t) {
        const int cb = t & 1;
        float4 c0 = sb[w][cb][3 * lane + 0];
        float4 c1 = sb[w][cb][3 * lane + 1];
        float4 c2 = sb[w][cb][3 * lane + 2];
        float g0 = gray1(c0.x, c0.y, c0.z);
        float g1 = gray1(c0.w, c1.x, c1.y);
        float g2 = gray1(c1.z, c1.w, c2.x);
        float g3 = gray1(c2.y, c2.z, c2.w);
        gray4[(size_t)gw * 256 + t * 64 + lane] = make_float4(g0, g1, g2, g3);
        unsigned k0 = fkey(g0), k1 = fkey(g1), k2 = fkey(g2), k3 = fkey(g3);
        mn = min(mn, min(min(k0, k1), min(k2, k3)));
        mx = max(mx, max(max(k0, k1), max(k2, k3)));
        if (t < 3) {
            sb[w][cb ^ 1][lane]       = a0;
            sb[w][cb ^ 1][64 + lane]  = a1;
            sb[w][cb ^ 1][128 + lane] = a2;
            if (t < 2) {
                a0 = in4[base + (size_t)(t + 2) * 192 + lane];
                a1 = in4[base + (size_t)(t + 2) * 192 + 64 + lane];
                a2 = in4[base + (size_t)(t + 2) * 192 + 128 + lane];
            }
            __builtin_amdgcn_sched_barrier(0);
        }
    }
    for (int off = 32; off > 0; off >>= 1) {
        mn = min(mn, (unsigned)__shfl_xor((int)mn, off, 64));
        mx = max(mx, (unsigned)__shfl_xor((int)mx, off, 64));
    }
    if (lane == 0) { smn[w] = mn; smx[w] = mx; }
    __syncthreads();
    if (threadIdx.x == 0) {
        mn = min(min(smn[0], smn[1]), min(smn[2], smn[3]));
        mx = max(max(smx[0], smx[1]), max(smx[2], smx[3]));
        wsu[SCRATCH_OFF + 2 * blockIdx.x]     = mn;
        wsu[SCRATCH_OFF + 2 * blockIdx.x + 1] = mx;
    }
}

__global__ void __launch_bounds__(256)
gray_minmax_generic(const float* __restrict__ in, float* __restrict__ gray,
                    unsigned* __restrict__ wsu, int npix4) {
    __shared__ unsigned smn[4], smx[4];
    const float4* in4 = (const float4*)in;
    const int stride = gridDim.x * blockDim.x;
    unsigned mn = 0xFFFFFFFFu, mx = 0u;
    for (int t = blockIdx.x * blockDim.x + threadIdx.x; t < npix4; t += stride) {
        const float4* p = in4 + (size_t)t * 3;
        float4 c0 = p[0], c1 = p[1], c2 = p[2];
        float g0 = gray1(c0.x, c0.y, c0.z);
        float g1 = gray1(c0.w, c1.x, c1.y);
        float g2 = gray1(c1.z, c1.w, c2.x);
        float g3 = gray1(c2.y, c2.z, c2.w);
        if (gray) ((float4*)gray)[t] = make_float4(g0, g1, g2, g3);
        unsigned k0 = fkey(g0), k1 = fkey(g1), k2 = fkey(g2), k3 = fkey(g3);
        mn = min(mn, min(min(k0, k1), min(k2, k3)));
        mx = max(mx, max(max(k0, k1), max(k2, k3)));
    }
    for (int off = 32; off > 0; off >>= 1) {
        mn = min(mn, (unsigned)__shfl_xor((int)mn, off, 64));
        mx = max(mx, (unsigned)__shfl_xor((int)mx, off, 64));
    }
    int wave = threadIdx.x >> 6;
    if ((threadIdx.x & 63) == 0) { smn[wave] = mn; smx[wave] = mx; }
    __syncthreads();
    if (threadIdx.x == 0) {
        mn = min(min(smn[0], smn[1]), min(smn[2], smn[3]));
        mx = max(max(smx[0], smx[1]), max(smx[2], smx[3]));
        atomicMin(&wsu[0], mn);
        atomicMax(&wsu[1], mx);
    }
}

__global__ void edges_kernel(unsigned* __restrict__ wsu,
                             float* __restrict__ wsf, int nblk) {
    __shared__ unsigned rmn[4], rmx[4];
    const int i = threadIdx.x;
    unsigned mn = 0xFFFFFFFFu, mx = 0u;
    if (nblk > 0) {
        for (int b = i; b < nblk; b += 256) {
            mn = min(mn, wsu[SCRATCH_OFF + 2 * b]);
            mx = max(mx, wsu[SCRATCH_OFF + 2 * b + 1]);
        }
        for (int off = 32; off > 0; off >>= 1) {
            mn = min(mn, (unsigned)__shfl_xor((int)mn, off, 64));
            mx = max(mx, (unsigned)__shfl_xor((int)mx, off, 64));
        }
        const int w = i >> 6;
        if ((i & 63) == 0) { rmn[w] = mn; rmx[w] = mx; }
        __syncthreads();
        mn = min(min(rmn[0], rmn[1]), min(rmn[2], rmn[3]));
        mx = max(max(rmx[0], rmx[1]), max(rmx[2], rmx[3]));
    } else {
        mn = wsu[0];
        mx = wsu[1];
    }
    const float vmin = keyf(mn);
    const float vmax = keyf(mx);
    const float delta = __fdiv_rn(__fsub_rn(vmax, vmin), 256.0f);
    wsf[EDGES_OFF + i] = __fadd_rn(vmin, __fmul_rn((float)i, delta));
    if (i == 0) {
        wsf[EDGES_OFF + 256] = vmax;
        wsf[VMIN_OFF]  = vmin;
        wsf[DELTA_OFF] = delta;
        wsf[INVD_OFF]  = (delta > 0.0f) ? __fdiv_rn(1.0f, delta) : 0.0f;
    }
}

__global__ void __launch_bounds__(256)
hist_kernel(const float* __restrict__ gray, const float* __restrict__ in,
            const float* __restrict__ wsf, unsigned* __restrict__ wsu,
            int npix4) {
    __shared__ float eds[257];
    __shared__ unsigned lh[256];
    for (int i = threadIdx.x; i < 257; i += blockDim.x)
        eds[i] = wsf[EDGES_OFF + i];
    if (threadIdx.x < 256) lh[threadIdx.x] = 0u;
    __syncthreads();
    const float vmin = eds[0];
    const float invd = wsf[INVD_OFF];
    const int stride = gridDim.x * blockDim.x;
    const int base = blockIdx.x * blockDim.x + threadIdx.x;
    if (gray && base + 7 * stride < npix4) {
        float4 g[8];
#pragma unroll
        for (int j = 0; j < 8; ++j) g[j] = ((const float4*)gray)[base + j * stride];
#pragma unroll
        for (int j = 0; j < 8; ++j)
            bin4(g[j].x, g[j].y, g[j].z, g[j].w, eds, vmin, invd, lh);
    } else {
        for (int t = base; t < npix4; t += stride) {
            float4 g4;
            if (gray) g4 = ((const float4*)gray)[t];
            else {
                const float4* p = (const float4*)in + (size_t)t * 3;
                float4 c0 = p[0], c1 = p[1], c2 = p[2];
                g4 = make_float4(gray1(c0.x, c0.y, c0.z), gray1(c0.w, c1.x, c1.y),
                                 gray1(c1.z, c1.w, c2.x), gray1(c2.y, c2.z, c2.w));
            }
            bin4(g4.x, g4.y, g4.z, g4.w, eds, vmin, invd, lh);
        }
    }
    __syncthreads();
    if (threadIdx.x < 256 && lh[threadIdx.x] != 0u)
        atomicAdd(&wsu[HIST_OFF + threadIdx.x], lh[threadIdx.x]);
}

__global__ void otsu_kernel(const unsigned* __restrict__ wsu,
                            float* __restrict__ wsf) {
    __shared__ float histf[256];
    __shared__ float centers[256];
    __shared__ float w2a[256];
    __shared__ float s2a[256];
    int i = threadIdx.x;
    float e0 = wsf[EDGES_OFF + i];
    float e1 = wsf[EDGES_OFF + i + 1];
    centers[i] = __fmul_rn(__fadd_rn(e0, e1), 0.5f);
    histf[i] = (float)wsu[HIST_OFF + i];
    __syncthreads();
    if (i == 0) {
        float w = 0.0f, s = 0.0f;
        for (int t = 255; t >= 0; --t) {
            w = __fadd_rn(w, histf[t]);
            s = __fadd_rn(s, __fmul_rn(histf[t], centers[t]));
            w2a[t] = w;
            s2a[t] = s;
        }
        float w1 = 0.0f, s1 = 0.0f, best = -1.0f;
        int bidx = 0;
        for (int t = 0; t < 255; ++t) {
            w1 = __fadd_rn(w1, histf[t]);
            s1 = __fadd_rn(s1, __fmul_rn(histf[t], centers[t]));
            float m1 = __fdiv_rn(s1, fmaxf(w1, 1.0f));
            float m2 = __fdiv_rn(s2a[t + 1], fmaxf(w2a[t + 1], 1.0f));
            float d  = __fsub_rn(m1, m2);
            float v  = __fmul_rn(__fmul_rn(w1, w2a[t + 1]), __fmul_rn(d, d));
            if (v > best) { best = v; bidx = t; }
        }
        wsf[THRESH_OFF] = centers[bidx];
    }
}

__global__ void __launch_bounds__(256)
binarize_fast(const float* __restrict__ gray, const float* __restrict__ wsf,
              float* __restrict__ out, int npix4) {
    const float thr = wsf[THRESH_OFF];
    const nfloat4* gray4 = (const nfloat4*)gray;
    nfloat4* out4 = (nfloat4*)out;
    const int lane = threadIdx.x & 63;
    const int gw = (blockIdx.x * blockDim.x + threadIdx.x) >> 6;
    const int ma = lane / 3,         qa = lane % 3;
    const int mb = (64 + lane) / 3,  qb = (64 + lane) % 3;
    const int mc = (128 + lane) / 3, qc = (128 + lane) % 3;

    nfloat4 g[4];
    bool full[4];
#pragma unroll
    for (int r = 0; r < 4; ++r) {
        int gbase = gw * 256 + r * 64;
        full[r] = (gbase + 64 <= npix4);
        if (full[r]) g[r] = gray4[gbase + lane];
    }
#pragma unroll
    for (int r = 0; r < 4; ++r) {
        const int gbase = gw * 256 + r * 64;
        if (full[r]) {
            unsigned u = (g[r].x > thr ? 1u : 0u) |
                         (g[r].y > thr ? 0x100u : 0u) |
                         (g[r].z > thr ? 0x10000u : 0u) |
                         (g[r].w > thr ? 0x1000000u : 0u);
            const int rb = 3 * gbase;
#pragma unroll
            for (int k = 0; k < 3; ++k) {
                int m = (k == 0) ? ma : (k == 1) ? mb : mc;
                int q = (k == 0) ? qa : (k == 1) ? qb : qc;
                unsigned x = (unsigned)__builtin_amdgcn_ds_bpermute(4 * m,
                                                                    (int)u);
                float h0 = (x & 0xffu)       ? 1.0f : 0.0f;
                float h1 = (x & 0xff00u)     ? 1.0f : 0.0f;
                float h2 = (x & 0xff0000u)   ? 1.0f : 0.0f;
                float h3 = (x & 0xff000000u) ? 1.0f : 0.0f;
                nfloat4 o;
                o.x = (q == 0) ? h0 : (q == 1) ? h1 : h2;
                o.y = (q == 0) ? h0 : (q == 1) ? h1 : h3;
                o.z = (q == 0) ? h0 : (q == 1) ? h2 : h3;
                o.w = (q == 0) ? h1 : (q == 1) ? h2 : h3;
                __builtin_nontemporal_store(o, &out4[rb + 64 * k + lane]);
            }
        } else {
            int t = gbase + lane;
            if (t < npix4) {
                nfloat4 gg = gray4[t];
                float b0 = (gg.x > thr) ? 1.0f : 0.0f;
                float b1 = (gg.y > thr) ? 1.0f : 0.0f;
                float b2 = (gg.z > thr) ? 1.0f : 0.0f;
                float b3 = (gg.w > thr) ? 1.0f : 0.0f;
                nfloat4* o = out4 + (size_t)t * 3;
                __builtin_nontemporal_store((nfloat4){b0, b0, b0, b1}, &o[0]);
                __builtin_nontemporal_store((nfloat4){b1, b1, b2, b2}, &o[1]);
                __builtin_nontemporal_store((nfloat4){b2, b3, b3, b3}, &o[2]);
            }
        }
    }
}

__global__ void __launch_bounds__(256)
binarize_generic(const float* __restrict__ gray, const float* __restrict__ in,
                 const float* __restrict__ wsf, float* __restrict__ out,
                 int npix4) {
    const float thr = wsf[THRESH_OFF];
    const int stride = gridDim.x * blockDim.x;
    nfloat4* out4 = (nfloat4*)out;
    for (int t = blockIdx.x * blockDim.x + threadIdx.x; t < npix4; t += stride) {
        float4 g4;
        if (gray) g4 = ((const float4*)gray)[t];
        else {
            const float4* p = (const float4*)in + (size_t)t * 3;
            float4 c0 = p[0], c1 = p[1], c2 = p[2];
            g4 = make_float4(gray1(c0.x, c0.y, c0.z), gray1(c0.w, c1.x, c1.y),
                             gray1(c1.z, c1.w, c2.x), gray1(c2.y, c2.z, c2.w));
        }
        float b0 = (g4.x > thr) ? 1.0f : 0.0f;
        float b1 = (g4.y > thr) ? 1.0f : 0.0f;
        float b2 = (g4.z > thr) ? 1.0f : 0.0f;
        float b3 = (g4.w > thr) ? 1.0f : 0.0f;
        nfloat4* o = out4 + (size_t)t * 3;
        o[0] = (nfloat4){b0, b0, b0, b1};
        o[1] = (nfloat4){b1, b1, b2, b2};
        o[2] = (nfloat4){b2, b3, b3, b3};
    }
}

static void launch_fallback(const float* in, float* out, unsigned* wsu,
                            float* wsf, float* gray, int npix4,
                            hipStream_t stream) {
    hipLaunchKernelGGL(init_kernel, dim3(1), dim3(256), 0, stream, wsu);
    int nblk = 0;
    if (gray && npix4 % 1024 == 0) {
        nblk = npix4 / 1024;
        hipLaunchKernelGGL(gray_minmax_lds, dim3(nblk), dim3(256), 0,
                           stream, in, gray, wsu, npix4);
    } else {
        hipLaunchKernelGGL(gray_minmax_generic, dim3(2048), dim3(256), 0,
                           stream, in, gray, wsu, npix4);
    }
    hipLaunchKernelGGL(edges_kernel, dim3(1), dim3(256), 0, stream, wsu, wsf,
                       nblk);
    hipLaunchKernelGGL(hist_kernel, dim3(1024), dim3(256), 0, stream,
                       gray, in, wsf, wsu, npix4);
    hipLaunchKernelGGL(otsu_kernel, dim3(1), dim3(256), 0, stream, wsu, wsf);
    if (gray) {
        hipLaunchKernelGGL(binarize_fast, dim3((npix4 + 1023) / 1024),
                           dim3(256), 0, stream, gray, wsf, out, npix4);
    } else {
        hipLaunchKernelGGL(binarize_generic, dim3(2048), dim3(256), 0, stream,
                           gray, in, wsf, out, npix4);
    }
}

extern "C" void kernel_launch(void* const* d_in, const int* in_sizes, int n_in,
                              void* d_out, int out_size, void* d_ws,
                              size_t ws_size, hipStream_t stream) {
    const float* in = (const float*)d_in[0];
    float* out = (float*)d_out;
    int npix  = out_size / 3;
    int npix4 = npix / 4;
    unsigned* wsu = (unsigned*)d_ws;
    float* wsf = (float*)d_ws;
    size_t need = GRAY_BYTE_OFF + (size_t)npix * sizeof(float);
    float* gray = (ws_size >= need)
                      ? (float*)((char*)d_ws + GRAY_BYTE_OFF)
                      : nullptr;

    // cooperative-capacity query (host-only, cached; safe under graph capture)
    static int capacity = -2;
    if (capacity == -2) {
        capacity = -1;
        int dev = 0, nb = 0;
        hipDeviceProp_t prop;
        if (hipGetDevice(&dev) == hipSuccess &&
            hipGetDeviceProperties(&prop, dev) == hipSuccess &&
            hipOccupancyMaxActiveBlocksPerMultiprocessor(
                &nb, (const void*)fused_otsu, 256, 0) == hipSuccess)
            capacity = nb * prop.multiProcessorCount;
    }

    const int NB = npix4 / 2048;
    const bool fused_ok = (npix4 % 2048 == 0) && NB >= 1 && capacity >= NB &&
                          ws_size >= (size_t)4096 + 8u * (size_t)NB;
    if (fused_ok) {
        int nb_arg = NB;
        void* args[] = {(void*)&in, (void*)&out, (void*)&wsu, (void*)&wsf,
                        (void*)&nb_arg};
        hipError_t e = hipLaunchCooperativeKernel(
            (const void*)fused_otsu, dim3(NB), dim3(256), args, 0, stream);
        if (e == hipSuccess) return;
    }
    launch_fallback(in, out, wsu, wsf, gray, npix4, stream);
}

// Round 5
// 237.848 us; speedup vs baseline: 1.1676x; 1.0891x over previous
//
#include <hip/hip_runtime.h>

// ---------------- workspace layout (indices into uint32/float32 view) -------
// wsu[0] = min key, wsu[1] = max key (fallback/atomic path only)
// wsu[2..257]   = hist[256]
// wsf[258..514] = edges[257]      (fallback path)
// wsf[515] = vmin, wsf[516] = delta, wsf[517] = inv_delta, wsf[518] = thresh
// wsu[1024 .. 1024+2*npairs) = per-block (mn,mx) key pairs
// byte offset 32768: gray[npix]
static constexpr int HIST_OFF    = 2;
static constexpr int EDGES_OFF   = 258;
static constexpr int VMIN_OFF    = 515;
static constexpr int DELTA_OFF   = 516;
static constexpr int INVD_OFF    = 517;
static constexpr int THRESH_OFF  = 518;
static constexpr int SCRATCH_OFF = 1024;         // per-block minmax pairs
static constexpr size_t GRAY_BYTE_OFF = 32768;

typedef float nfloat4 __attribute__((ext_vector_type(4)));

__device__ __forceinline__ unsigned fkey(float x) {
    unsigned u = __float_as_uint(x);
    return (u & 0x80000000u) ? ~u : (u | 0x80000000u);
}
__device__ __forceinline__ float keyf(unsigned k) {
    return (k & 0x80000000u) ? __uint_as_float(k & 0x7FFFFFFFu)
                             : __uint_as_float(~k);
}
// gray = ((r*wr + g*wg) + b*wb), strict f32 rounding, NO fma contraction
__device__ __forceinline__ float gray1(float r, float g, float b) {
    float t0 = __fmul_rn(r, 0.2989f);
    float t1 = __fmul_rn(g, 0.5870f);
    float t2 = __fmul_rn(b, 0.1140f);
    return __fadd_rn(__fadd_rn(t0, t1), t2);
}

__device__ __forceinline__ void bin4(float x0, float x1, float x2, float x3,
                                     const float* eds, float vmin, float invd,
                                     unsigned* lh) {
    float xs[4] = {x0, x1, x2, x3};
#pragma unroll
    for (int j = 0; j < 4; ++j) {
        float x = xs[j];
        int b = (int)(__fmul_rn(__fsub_rn(x, vmin), invd));
        b = b < 0 ? 0 : (b > 255 ? 255 : b);
        while (b < 255 && x >= eds[b + 1]) ++b;   // exact searchsorted fixup
        while (b > 0 && x < eds[b]) --b;
        atomicAdd(&lh[b], 1u);
    }
}

// block-wide reduce of the per-block (mn,mx) scratch pairs. All threads get
// the final result. Pairs are L2-resident (8 KB) -> ~2 us redundant per block.
__device__ __forceinline__ void reduce_pairs(const unsigned* __restrict__ wsu,
                                             int npairs, int t,
                                             unsigned& mn, unsigned& mx,
                                             unsigned* rmn, unsigned* rmx) {
    mn = 0xFFFFFFFFu; mx = 0u;
    for (int i = t; i < npairs; i += 256) {
        mn = min(mn, wsu[SCRATCH_OFF + 2 * i]);
        mx = max(mx, wsu[SCRATCH_OFF + 2 * i + 1]);
    }
    for (int off = 32; off > 0; off >>= 1) {
        mn = min(mn, (unsigned)__shfl_xor((int)mn, off, 64));
        mx = max(mx, (unsigned)__shfl_xor((int)mx, off, 64));
    }
    const int w = t >> 6;
    if ((t & 63) == 0) { rmn[w] = mn; rmx[w] = mx; }
    __syncthreads();
    mn = min(min(rmn[0], rmn[1]), min(rmn[2], rmn[3]));
    mx = max(max(rmx[0], rmx[1]), max(rmx[2], rmx[3]));
}

// =============== R11: 3-kernel pipeline (no cooperative launch) =============
// R4 post-mortem: fused cooperative kernel = 307 us in rocprof (grid-sync +
// same latency-bound loads, no win) AND hipLaunchCooperativeKernel fails
// under the harness's graph capture (timed run fell back, 259 us). The 6-
// dispatch pipeline's device work sums to ~110 us; the rest is dispatch
// boundaries + two serial single-block kernels. Fix without grid-sync:
// fold init into K1 (block 0 zeroes hist), edges into K2, otsu into K3 --
// each block redundantly recomputes the tiny reductions (8 KB pairs / 1 KB
// hist, L2-resident). Cross-kernel visibility = stream order. 6 -> 3
// dispatches, single-block serial kernels eliminated.

// ---------- K1: gray + per-block minmax (R2/R3 structure, proven) -----------
__global__ void __launch_bounds__(256)
gray_minmax_lds(const float* __restrict__ in, float* __restrict__ gray,
                unsigned* __restrict__ wsu, int npix4) {
    __shared__ float4 sb[4][2][192];
    __shared__ unsigned smn[4], smx[4];
    const float4* __restrict__ in4 = (const float4*)in;
    float4* __restrict__ gray4 = (float4*)gray;
    const int lane = threadIdx.x & 63;
    const int w = threadIdx.x >> 6;
    const int gw = blockIdx.x * 4 + w;
    const size_t base = (size_t)gw * 768;
    unsigned mn = 0xFFFFFFFFu, mx = 0u;

    // fold init_kernel: block 0 zeroes the global hist (visible to K2 via
    // stream ordering; no intra-grid dependence)
    if (blockIdx.x == 0) wsu[HIST_OFF + threadIdx.x] = 0u;

    float4 a0 = in4[base + lane];
    float4 a1 = in4[base + 64 + lane];
    float4 a2 = in4[base + 128 + lane];
    __builtin_amdgcn_sched_barrier(0);
    sb[w][0][lane]       = a0;
    sb[w][0][64 + lane]  = a1;
    sb[w][0][128 + lane] = a2;
    a0 = in4[base + 192 + lane];
    a1 = in4[base + 256 + lane];
    a2 = in4[base + 320 + lane];
    __builtin_amdgcn_sched_barrier(0);

#pragma unroll
    for (int t = 0; t < 4; ++t) {
        const int cb = t & 1;
        float4 c0 = sb[w][cb][3 * lane + 0];
        float4 c1 = sb[w][cb][3 * lane + 1];
        float4 c2 = sb[w][cb][3 * lane + 2];
        float g0 = gray1(c0.x, c0.y, c0.z);
        float g1 = gray1(c0.w, c1.x, c1.y);
        float g2 = gray1(c1.z, c1.w, c2.x);
        float g3 = gray1(c2.y, c2.z, c2.w);
        gray4[(size_t)gw * 256 + t * 64 + lane] = make_float4(g0, g1, g2, g3);
        unsigned k0 = fkey(g0), k1 = fkey(g1), k2 = fkey(g2), k3 = fkey(g3);
        mn = min(mn, min(min(k0, k1), min(k2, k3)));
        mx = max(mx, max(max(k0, k1), max(k2, k3)));
        if (t < 3) {
            sb[w][cb ^ 1][lane]       = a0;
            sb[w][cb ^ 1][64 + lane]  = a1;
            sb[w][cb ^ 1][128 + lane] = a2;
            if (t < 2) {
                a0 = in4[base + (size_t)(t + 2) * 192 + lane];
                a1 = in4[base + (size_t)(t + 2) * 192 + 64 + lane];
                a2 = in4[base + (size_t)(t + 2) * 192 + 128 + lane];
            }
            __builtin_amdgcn_sched_barrier(0);
        }
    }
    for (int off = 32; off > 0; off >>= 1) {
        mn = min(mn, (unsigned)__shfl_xor((int)mn, off, 64));
        mx = max(mx, (unsigned)__shfl_xor((int)mx, off, 64));
    }
    if (lane == 0) { smn[w] = mn; smx[w] = mx; }
    __syncthreads();
    if (threadIdx.x == 0) {
        mn = min(min(smn[0], smn[1]), min(smn[2], smn[3]));
        mx = max(max(smx[0], smx[1]), max(smx[2], smx[3]));
        wsu[SCRATCH_OFF + 2 * blockIdx.x]     = mn;
        wsu[SCRATCH_OFF + 2 * blockIdx.x + 1] = mx;
    }
}

// ---------- K2: per-block edges recompute + hist ----------------------------
// grid = npix4/2048 blocks; each thread: 8 coalesced gray-float4 loads.
__global__ void __launch_bounds__(256)
hist_fused(const float* __restrict__ gray, unsigned* __restrict__ wsu,
           int npairs, int npix4) {
    __shared__ float eds[257];
    __shared__ unsigned lh[256];
    __shared__ unsigned rmn[4], rmx[4];
    const int t = threadIdx.x;
    unsigned mn, mx;
    reduce_pairs(wsu, npairs, t, mn, mx, rmn, rmx);
    const float vmin = keyf(mn);
    const float vmax = keyf(mx);
    const float delta = __fdiv_rn(__fsub_rn(vmax, vmin), 256.0f);
    const float invd = (delta > 0.0f) ? __fdiv_rn(1.0f, delta) : 0.0f;
    eds[t] = __fadd_rn(vmin, __fmul_rn((float)t, delta));
    if (t == 0) eds[256] = vmax;
    lh[t] = 0u;
    __syncthreads();

    const int stride = gridDim.x * 256;
    const int base = blockIdx.x * 256 + t;
    float4 g[8];
#pragma unroll
    for (int j = 0; j < 8; ++j) g[j] = ((const float4*)gray)[base + j * stride];
#pragma unroll
    for (int j = 0; j < 8; ++j)
        bin4(g[j].x, g[j].y, g[j].z, g[j].w, eds, vmin, invd, lh);
    __syncthreads();
    if (lh[t] != 0u) atomicAdd(&wsu[HIST_OFF + t], lh[t]);
}

// ---------- K3: per-block Otsu recompute + binarize -------------------------
// grid = npix4/2048 blocks; per wave 8 rounds of 64 gray4 groups.
// Otsu preamble: serial cumsums on thread 0 (order-faithful to numpy),
// 255 independent variance evals on 255 threads, first-max argmax reduce
// (smaller-index tie-break == serial "v > best" first-max scan).
__global__ void __launch_bounds__(256)
binarize_fused(const float* __restrict__ gray, const unsigned* __restrict__ wsu,
               float* __restrict__ out, int npairs, int npix4) {
    __shared__ float eds[257];
    __shared__ float histf[256], centers[256];
    __shared__ float w1a[256], s1a[256], w2a[256], s2a[256];
    __shared__ unsigned rmn[4], rmx[4];
    __shared__ float rbv[4];
    __shared__ int rbi[4];
    __shared__ float sthresh;
    const int t = threadIdx.x;
    const int lane = t & 63;
    const int w = t >> 6;

    unsigned mn, mx;
    reduce_pairs(wsu, npairs, t, mn, mx, rmn, rmx);
    const float vmin = keyf(mn);
    const float vmax = keyf(mx);
    const float delta = __fdiv_rn(__fsub_rn(vmax, vmin), 256.0f);
    eds[t] = __fadd_rn(vmin, __fmul_rn((float)t, delta));
    if (t == 0) eds[256] = vmax;
    histf[t] = (float)wsu[HIST_OFF + t];
    __syncthreads();
    centers[t] = __fmul_rn(__fadd_rn(eds[t], eds[t + 1]), 0.5f);
    __syncthreads();
    if (t == 0) {
        float ww = 0.0f, ss = 0.0f;
        for (int k = 255; k >= 0; --k) {           // backward cumsums (exact)
            ww = __fadd_rn(ww, histf[k]);
            ss = __fadd_rn(ss, __fmul_rn(histf[k], centers[k]));
            w2a[k] = ww;
            s2a[k] = ss;
        }
        ww = 0.0f; ss = 0.0f;
        for (int k = 0; k < 255; ++k) {            // forward cumsums (exact)
            ww = __fadd_rn(ww, histf[k]);
            ss = __fadd_rn(ss, __fmul_rn(histf[k], centers[k]));
            w1a[k] = ww;
            s1a[k] = ss;
        }
    }
    __syncthreads();
    float v = -1.0f;
    int ti = 256;
    if (t < 255) {                                 // parallel variance evals
        float m1 = __fdiv_rn(s1a[t], fmaxf(w1a[t], 1.0f));
        float m2 = __fdiv_rn(s2a[t + 1], fmaxf(w2a[t + 1], 1.0f));
        float d  = __fsub_rn(m1, m2);
        v  = __fmul_rn(__fmul_rn(w1a[t], w2a[t + 1]), __fmul_rn(d, d));
        ti = t;
    }
    for (int off = 32; off > 0; off >>= 1) {       // first-max argmax reduce
        float ov = __shfl_xor(v, off, 64);
        int oi = __shfl_xor(ti, off, 64);
        if (ov > v || (ov == v && oi < ti)) { v = ov; ti = oi; }
    }
    if (lane == 0) { rbv[w] = v; rbi[w] = ti; }
    __syncthreads();
    if (t == 0) {
        float bv = rbv[0]; int bi = rbi[0];
        for (int k = 1; k < 4; ++k)
            if (rbv[k] > bv || (rbv[k] == bv && rbi[k] < bi)) {
                bv = rbv[k]; bi = rbi[k];
            }
        sthresh = centers[bi];
    }
    __syncthreads();
    const float thr = sthresh;

    // binarize body (proven bpermute expand + NT full-line stores)
    const nfloat4* gray4 = (const nfloat4*)gray;
    nfloat4* out4 = (nfloat4*)out;
    const int gw = blockIdx.x * 4 + w;
    const int ma = lane / 3,         qa = lane % 3;
    const int mb = (64 + lane) / 3,  qb = (64 + lane) % 3;
    const int mc = (128 + lane) / 3, qc = (128 + lane) % 3;
#pragma unroll
    for (int r = 0; r < 8; ++r) {
        const int gbase = gw * 512 + r * 64;
        nfloat4 gg = gray4[gbase + lane];
        unsigned u = (gg.x > thr ? 1u : 0u) |
                     (gg.y > thr ? 0x100u : 0u) |
                     (gg.z > thr ? 0x10000u : 0u) |
                     (gg.w > thr ? 0x1000000u : 0u);
        const size_t rb = 3 * (size_t)gbase;
#pragma unroll
        for (int k = 0; k < 3; ++k) {
            int m = (k == 0) ? ma : (k == 1) ? mb : mc;
            int q = (k == 0) ? qa : (k == 1) ? qb : qc;
            unsigned x = (unsigned)__builtin_amdgcn_ds_bpermute(4 * m, (int)u);
            float h0 = (x & 0xffu)       ? 1.0f : 0.0f;
            float h1 = (x & 0xff00u)     ? 1.0f : 0.0f;
            float h2 = (x & 0xff0000u)   ? 1.0f : 0.0f;
            float h3 = (x & 0xff000000u) ? 1.0f : 0.0f;
            nfloat4 o;
            o.x = (q == 0) ? h0 : (q == 1) ? h1 : h2;
            o.y = (q == 0) ? h0 : (q == 1) ? h1 : h3;
            o.z = (q == 0) ? h0 : (q == 1) ? h2 : h3;
            o.w = (q == 0) ? h1 : (q == 1) ? h2 : h3;
            __builtin_nontemporal_store(o, &out4[rb + 64 * k + lane]);
        }
    }
}

// =============== fallback multi-kernel pipeline (R3, proven) ================

__global__ void init_kernel(unsigned* __restrict__ wsu) {
    int i = threadIdx.x;
    if (i < 256) wsu[HIST_OFF + i] = 0u;
    if (i == 0) { wsu[0] = 0xFFFFFFFFu; wsu[1] = 0u; }
}

__global__ void __launch_bounds__(256)
gray_minmax_generic(const float* __restrict__ in, float* __restrict__ gray,
                    unsigned* __restrict__ wsu, int npix4) {
    __shared__ unsigned smn[4], smx[4];
    const float4* in4 = (const float4*)in;
    const int stride = gridDim.x * blockDim.x;
    unsigned mn = 0xFFFFFFFFu, mx = 0u;
    for (int t = blockIdx.x * blockDim.x + threadIdx.x; t < npix4; t += stride) {
        const float4* p = in4 + (size_t)t * 3;
        float4 c0 = p[0], c1 = p[1], c2 = p[2];
        float g0 = gray1(c0.x, c0.y, c0.z);
        float g1 = gray1(c0.w, c1.x, c1.y);
        float g2 = gray1(c1.z, c1.w, c2.x);
        float g3 = gray1(c2.y, c2.z, c2.w);
        if (gray) ((float4*)gray)[t] = make_float4(g0, g1, g2, g3);
        unsigned k0 = fkey(g0), k1 = fkey(g1), k2 = fkey(g2), k3 = fkey(g3);
        mn = min(mn, min(min(k0, k1), min(k2, k3)));
        mx = max(mx, max(max(k0, k1), max(k2, k3)));
    }
    for (int off = 32; off > 0; off >>= 1) {
        mn = min(mn, (unsigned)__shfl_xor((int)mn, off, 64));
        mx = max(mx, (unsigned)__shfl_xor((int)mx, off, 64));
    }
    int wave = threadIdx.x >> 6;
    if ((threadIdx.x & 63) == 0) { smn[wave] = mn; smx[wave] = mx; }
    __syncthreads();
    if (threadIdx.x == 0) {
        mn = min(min(smn[0], smn[1]), min(smn[2], smn[3]));
        mx = max(max(smx[0], smx[1]), max(smx[2], smx[3]));
        atomicMin(&wsu[0], mn);
        atomicMax(&wsu[1], mx);
    }
}

__global__ void edges_kernel(unsigned* __restrict__ wsu,
                             float* __restrict__ wsf, int nblk) {
    __shared__ unsigned rmn[4], rmx[4];
    const int i = threadIdx.x;
    unsigned mn = 0xFFFFFFFFu, mx = 0u;
    if (nblk > 0) {
        for (int b = i; b < nblk; b += 256) {
            mn = min(mn, wsu[SCRATCH_OFF + 2 * b]);
            mx = max(mx, wsu[SCRATCH_OFF + 2 * b + 1]);
        }
        for (int off = 32; off > 0; off >>= 1) {
            mn = min(mn, (unsigned)__shfl_xor((int)mn, off, 64));
            mx = max(mx, (unsigned)__shfl_xor((int)mx, off, 64));
        }
        const int w = i >> 6;
        if ((i & 63) == 0) { rmn[w] = mn; rmx[w] = mx; }
        __syncthreads();
        mn = min(min(rmn[0], rmn[1]), min(rmn[2], rmn[3]));
        mx = max(max(rmx[0], rmx[1]), max(rmx[2], rmx[3]));
    } else {
        mn = wsu[0];
        mx = wsu[1];
    }
    const float vmin = keyf(mn);
    const float vmax = keyf(mx);
    const float delta = __fdiv_rn(__fsub_rn(vmax, vmin), 256.0f);
    wsf[EDGES_OFF + i] = __fadd_rn(vmin, __fmul_rn((float)i, delta));
    if (i == 0) {
        wsf[EDGES_OFF + 256] = vmax;
        wsf[VMIN_OFF]  = vmin;
        wsf[DELTA_OFF] = delta;
        wsf[INVD_OFF]  = (delta > 0.0f) ? __fdiv_rn(1.0f, delta) : 0.0f;
    }
}

__global__ void __launch_bounds__(256)
hist_kernel(const float* __restrict__ gray, const float* __restrict__ in,
            const float* __restrict__ wsf, unsigned* __restrict__ wsu,
            int npix4) {
    __shared__ float eds[257];
    __shared__ unsigned lh[256];
    for (int i = threadIdx.x; i < 257; i += blockDim.x)
        eds[i] = wsf[EDGES_OFF + i];
    if (threadIdx.x < 256) lh[threadIdx.x] = 0u;
    __syncthreads();
    const float vmin = eds[0];
    const float invd = wsf[INVD_OFF];
    const int stride = gridDim.x * blockDim.x;
    const int base = blockIdx.x * blockDim.x + threadIdx.x;
    for (int t = base; t < npix4; t += stride) {
        float4 g4;
        if (gray) g4 = ((const float4*)gray)[t];
        else {
            const float4* p = (const float4*)in + (size_t)t * 3;
            float4 c0 = p[0], c1 = p[1], c2 = p[2];
            g4 = make_float4(gray1(c0.x, c0.y, c0.z), gray1(c0.w, c1.x, c1.y),
                             gray1(c1.z, c1.w, c2.x), gray1(c2.y, c2.z, c2.w));
        }
        bin4(g4.x, g4.y, g4.z, g4.w, eds, vmin, invd, lh);
    }
    __syncthreads();
    if (threadIdx.x < 256 && lh[threadIdx.x] != 0u)
        atomicAdd(&wsu[HIST_OFF + threadIdx.x], lh[threadIdx.x]);
}

__global__ void otsu_kernel(const unsigned* __restrict__ wsu,
                            float* __restrict__ wsf) {
    __shared__ float histf[256];
    __shared__ float centers[256];
    __shared__ float w2a[256];
    __shared__ float s2a[256];
    int i = threadIdx.x;
    float e0 = wsf[EDGES_OFF + i];
    float e1 = wsf[EDGES_OFF + i + 1];
    centers[i] = __fmul_rn(__fadd_rn(e0, e1), 0.5f);
    histf[i] = (float)wsu[HIST_OFF + i];
    __syncthreads();
    if (i == 0) {
        float w = 0.0f, s = 0.0f;
        for (int t = 255; t >= 0; --t) {
            w = __fadd_rn(w, histf[t]);
            s = __fadd_rn(s, __fmul_rn(histf[t], centers[t]));
            w2a[t] = w;
            s2a[t] = s;
        }
        float w1 = 0.0f, s1 = 0.0f, best = -1.0f;
        int bidx = 0;
        for (int t = 0; t < 255; ++t) {
            w1 = __fadd_rn(w1, histf[t]);
            s1 = __fadd_rn(s1, __fmul_rn(histf[t], centers[t]));
            float m1 = __fdiv_rn(s1, fmaxf(w1, 1.0f));
            float m2 = __fdiv_rn(s2a[t + 1], fmaxf(w2a[t + 1], 1.0f));
            float d  = __fsub_rn(m1, m2);
            float v  = __fmul_rn(__fmul_rn(w1, w2a[t + 1]), __fmul_rn(d, d));
            if (v > best) { best = v; bidx = t; }
        }
        wsf[THRESH_OFF] = centers[bidx];
    }
}

__global__ void __launch_bounds__(256)
binarize_generic(const float* __restrict__ gray, const float* __restrict__ in,
                 const float* __restrict__ wsf, float* __restrict__ out,
                 int npix4) {
    const float thr = wsf[THRESH_OFF];
    const int stride = gridDim.x * blockDim.x;
    nfloat4* out4 = (nfloat4*)out;
    for (int t = blockIdx.x * blockDim.x + threadIdx.x; t < npix4; t += stride) {
        float4 g4;
        if (gray) g4 = ((const float4*)gray)[t];
        else {
            const float4* p = (const float4*)in + (size_t)t * 3;
            float4 c0 = p[0], c1 = p[1], c2 = p[2];
            g4 = make_float4(gray1(c0.x, c0.y, c0.z), gray1(c0.w, c1.x, c1.y),
                             gray1(c1.z, c1.w, c2.x), gray1(c2.y, c2.z, c2.w));
        }
        float b0 = (g4.x > thr) ? 1.0f : 0.0f;
        float b1 = (g4.y > thr) ? 1.0f : 0.0f;
        float b2 = (g4.z > thr) ? 1.0f : 0.0f;
        float b3 = (g4.w > thr) ? 1.0f : 0.0f;
        nfloat4* o = out4 + (size_t)t * 3;
        o[0] = (nfloat4){b0, b0, b0, b1};
        o[1] = (nfloat4){b1, b1, b2, b2};
        o[2] = (nfloat4){b2, b3, b3, b3};
    }
}

static void launch_fallback(const float* in, float* out, unsigned* wsu,
                            float* wsf, float* gray, int npix4,
                            hipStream_t stream) {
    hipLaunchKernelGGL(init_kernel, dim3(1), dim3(256), 0, stream, wsu);
    hipLaunchKernelGGL(gray_minmax_generic, dim3(2048), dim3(256), 0,
                       stream, in, gray, wsu, npix4);
    hipLaunchKernelGGL(edges_kernel, dim3(1), dim3(256), 0, stream, wsu, wsf,
                       0);
    hipLaunchKernelGGL(hist_kernel, dim3(1024), dim3(256), 0, stream,
                       gray, in, wsf, wsu, npix4);
    hipLaunchKernelGGL(otsu_kernel, dim3(1), dim3(256), 0, stream, wsu, wsf);
    hipLaunchKernelGGL(binarize_generic, dim3(2048), dim3(256), 0, stream,
                       gray, in, wsf, out, npix4);
}

extern "C" void kernel_launch(void* const* d_in, const int* in_sizes, int n_in,
                              void* d_out, int out_size, void* d_ws,
                              size_t ws_size, hipStream_t stream) {
    const float* in = (const float*)d_in[0];
    float* out = (float*)d_out;
    int npix  = out_size / 3;
    int npix4 = npix / 4;
    unsigned* wsu = (unsigned*)d_ws;
    float* wsf = (float*)d_ws;
    size_t need = GRAY_BYTE_OFF + (size_t)npix * sizeof(float);
    float* gray = (ws_size >= need)
                      ? (float*)((char*)d_ws + GRAY_BYTE_OFF)
                      : nullptr;

    const bool fast = gray && (npix4 % 2048 == 0);
    if (fast) {
        const int npairs = npix4 / 1024;          // K1 grid / scratch pairs
        const int nb2 = npix4 / 2048;             // K2/K3 grid
        hipLaunchKernelGGL(gray_minmax_lds, dim3(npairs), dim3(256), 0,
                           stream, in, gray, wsu, npix4);
        hipLaunchKernelGGL(hist_fused, dim3(nb2), dim3(256), 0, stream,
                           gray, wsu, npairs, npix4);
        hipLaunchKernelGGL(binarize_fused, dim3(nb2), dim3(256), 0, stream,
                           gray, wsu, out, npairs, npix4);
    } else {
        launch_fallback(in, out, wsu, wsf, gray, npix4, stream);
    }
}

// Round 6
// 237.490 us; speedup vs baseline: 1.1694x; 1.0015x over previous
//
#include <hip/hip_runtime.h>

// ---------------- workspace layout (indices into uint32/float32 view) -------
// wsu[0] = min key, wsu[1] = max key (fallback/atomic path only)
// wsu[2..257]   = hist[256]
// wsu[300]/[301] = spin-barrier counters A/B (fused path; zeroed by memset)
// wsf[258..514] = edges[257]      (fallback path)
// wsf[515] = vmin, wsf[516] = delta, wsf[517] = inv_delta, wsf[518] = thresh
// wsu[1024 .. 1024+2*npairs) = per-block (mn,mx) key pairs
// byte offset 32768: gray[npix]  (3-kernel fallback path only)
static constexpr int HIST_OFF    = 2;
static constexpr int EDGES_OFF   = 258;
static constexpr int VMIN_OFF    = 515;
static constexpr int DELTA_OFF   = 516;
static constexpr int INVD_OFF    = 517;
static constexpr int THRESH_OFF  = 518;
static constexpr int CTRA_OFF    = 300;
static constexpr int CTRB_OFF    = 301;
static constexpr int SCRATCH_OFF = 1024;         // per-block minmax pairs
static constexpr size_t GRAY_BYTE_OFF = 32768;

typedef float nfloat4 __attribute__((ext_vector_type(4)));

__device__ __forceinline__ unsigned fkey(float x) {
    unsigned u = __float_as_uint(x);
    return (u & 0x80000000u) ? ~u : (u | 0x80000000u);
}
__device__ __forceinline__ float keyf(unsigned k) {
    return (k & 0x80000000u) ? __uint_as_float(k & 0x7FFFFFFFu)
                             : __uint_as_float(~k);
}
// gray = ((r*wr + g*wg) + b*wb), strict f32 rounding, NO fma contraction
__device__ __forceinline__ float gray1(float r, float g, float b) {
    float t0 = __fmul_rn(r, 0.2989f);
    float t1 = __fmul_rn(g, 0.5870f);
    float t2 = __fmul_rn(b, 0.1140f);
    return __fadd_rn(__fadd_rn(t0, t1), t2);
}

__device__ __forceinline__ void bin4(float x0, float x1, float x2, float x3,
                                     const float* eds, float vmin, float invd,
                                     unsigned* lh) {
    float xs[4] = {x0, x1, x2, x3};
#pragma unroll
    for (int j = 0; j < 4; ++j) {
        float x = xs[j];
        int b = (int)(__fmul_rn(__fsub_rn(x, vmin), invd));
        b = b < 0 ? 0 : (b > 255 ? 255 : b);
        while (b < 255 && x >= eds[b + 1]) ++b;   // exact searchsorted fixup
        while (b > 0 && x < eds[b]) --b;
        atomicAdd(&lh[b], 1u);
    }
}

// hand-rolled grid barrier: agent-scope atomic counter + s_sleep spin.
// NO plain-store visibility is implied (unlike cg::grid.sync(), which must
// flush the non-coherent per-XCD L2s -- R4's 307us lesson). All cross-block
// data in the fused kernel moves via agent-scope atomics, which operate at
// the coherent point, so this barrier is sufficient AND cheap.
__device__ __forceinline__ void gbar(unsigned* ctr, unsigned nblk) {
    __syncthreads();
    if (threadIdx.x == 0) {
        __hip_atomic_fetch_add(ctr, 1u, __ATOMIC_ACQ_REL,
                               __HIP_MEMORY_SCOPE_AGENT);
        while (__hip_atomic_load(ctr, __ATOMIC_ACQUIRE,
                                 __HIP_MEMORY_SCOPE_AGENT) < nblk)
            __builtin_amdgcn_s_sleep(2);
    }
    __syncthreads();
}

// =============== R12: single fused kernel, hand-rolled barriers =============
// Traffic: in 100.7 MB + out 100.7 MB = 201 MB; gray lives in 32 VGPRs per
// thread across all phases (the 33.6 MB write + 2x33.6 MB reads of the
// 3-kernel pipeline are gone), and 2 dispatch boundaries disappear.
// Requires npix4 % 2048 == 0 and all nblk blocks co-resident (4 blocks/CU
// via __launch_bounds__(256,4), verified by cached host occupancy query).
__global__ void __launch_bounds__(256, 4)
fused_all(const float* __restrict__ in, float* __restrict__ out,
          unsigned* __restrict__ wsu, int nblk) {
    __shared__ float eds[257];
    __shared__ unsigned lh[256];
    __shared__ float histf[256], centers[256];
    __shared__ float w1a[256], s1a[256], w2a[256], s2a[256];
    __shared__ unsigned rmn[4], rmx[4];
    __shared__ float rbv[4];
    __shared__ int rbi[4];
    __shared__ float sthresh;

    const int t = threadIdx.x;
    const int lane = t & 63;
    const int w = t >> 6;
    const int b = blockIdx.x;
    const int gw = b * 4 + w;                     // global wave id
    const float4* __restrict__ in4 = (const float4*)in;
    nfloat4* __restrict__ out4 = (nfloat4*)out;

    // ---- P0: gray + minmax; gray stays in registers ------------------------
    // wave owns 8 chunks of 64 consecutive float4-groups (matches binarize's
    // bpermute layout). Lane reads 3 consecutive float4s (48 B).
    nfloat4 gg[8];
    unsigned mn = 0xFFFFFFFFu, mx = 0u;
#pragma unroll
    for (int r = 0; r < 8; ++r) {
        const int grp = gw * 512 + r * 64 + lane;
        const float4* p = in4 + 3 * (size_t)grp;
        float4 c0 = p[0], c1 = p[1], c2 = p[2];
        float g0 = gray1(c0.x, c0.y, c0.z);
        float g1 = gray1(c0.w, c1.x, c1.y);
        float g2 = gray1(c1.z, c1.w, c2.x);
        float g3 = gray1(c2.y, c2.z, c2.w);
        gg[r].x = g0; gg[r].y = g1; gg[r].z = g2; gg[r].w = g3;
        unsigned k0 = fkey(g0), k1 = fkey(g1), k2 = fkey(g2), k3 = fkey(g3);
        mn = min(mn, min(min(k0, k1), min(k2, k3)));
        mx = max(mx, max(max(k0, k1), max(k2, k3)));
    }
    for (int off = 32; off > 0; off >>= 1) {
        mn = min(mn, (unsigned)__shfl_xor((int)mn, off, 64));
        mx = max(mx, (unsigned)__shfl_xor((int)mx, off, 64));
    }
    if (lane == 0) { rmn[w] = mn; rmx[w] = mx; }
    __syncthreads();
    if (t == 0) {
        mn = min(min(rmn[0], rmn[1]), min(rmn[2], rmn[3]));
        mx = max(max(rmx[0], rmx[1]), max(rmx[2], rmx[3]));
        __hip_atomic_store(&wsu[SCRATCH_OFF + 2 * b], mn, __ATOMIC_RELAXED,
                           __HIP_MEMORY_SCOPE_AGENT);
        __hip_atomic_store(&wsu[SCRATCH_OFF + 2 * b + 1], mx, __ATOMIC_RELAXED,
                           __HIP_MEMORY_SCOPE_AGENT);
    }
    gbar(&wsu[CTRA_OFF], (unsigned)nblk);

    // ---- P1: redundant pair-reduce -> edges; LDS hist from regs ------------
    mn = 0xFFFFFFFFu; mx = 0u;
    for (int i = t; i < nblk; i += 256) {
        mn = min(mn, __hip_atomic_load(&wsu[SCRATCH_OFF + 2 * i],
                                       __ATOMIC_RELAXED,
                                       __HIP_MEMORY_SCOPE_AGENT));
        mx = max(mx, __hip_atomic_load(&wsu[SCRATCH_OFF + 2 * i + 1],
                                       __ATOMIC_RELAXED,
                                       __HIP_MEMORY_SCOPE_AGENT));
    }
    for (int off = 32; off > 0; off >>= 1) {
        mn = min(mn, (unsigned)__shfl_xor((int)mn, off, 64));
        mx = max(mx, (unsigned)__shfl_xor((int)mx, off, 64));
    }
    if (lane == 0) { rmn[w] = mn; rmx[w] = mx; }
    __syncthreads();
    mn = min(min(rmn[0], rmn[1]), min(rmn[2], rmn[3]));
    mx = max(max(rmx[0], rmx[1]), max(rmx[2], rmx[3]));
    const float vmin = keyf(mn);
    const float vmax = keyf(mx);
    const float delta = __fdiv_rn(__fsub_rn(vmax, vmin), 256.0f);
    const float invd = (delta > 0.0f) ? __fdiv_rn(1.0f, delta) : 0.0f;
    eds[t] = __fadd_rn(vmin, __fmul_rn((float)t, delta));
    if (t == 0) eds[256] = vmax;
    lh[t] = 0u;
    __syncthreads();
#pragma unroll
    for (int r = 0; r < 8; ++r)
        bin4(gg[r].x, gg[r].y, gg[r].z, gg[r].w, eds, vmin, invd, lh);
    __syncthreads();
    if (lh[t] != 0u) atomicAdd(&wsu[HIST_OFF + t], lh[t]);  // agent-scope RMW
    gbar(&wsu[CTRB_OFF], (unsigned)nblk);

    // ---- P2: redundant per-block Otsu; binarize from registers -------------
    histf[t] = (float)__hip_atomic_load(&wsu[HIST_OFF + t], __ATOMIC_RELAXED,
                                        __HIP_MEMORY_SCOPE_AGENT);
    centers[t] = __fmul_rn(__fadd_rn(eds[t], eds[t + 1]), 0.5f);
    __syncthreads();
    if (t == 0) {
        float ww = 0.0f, ss = 0.0f;
        for (int k = 255; k >= 0; --k) {           // backward cumsums (exact)
            ww = __fadd_rn(ww, histf[k]);
            ss = __fadd_rn(ss, __fmul_rn(histf[k], centers[k]));
            w2a[k] = ww;
            s2a[k] = ss;
        }
        ww = 0.0f; ss = 0.0f;
        for (int k = 0; k < 255; ++k) {            // forward cumsums (exact)
            ww = __fadd_rn(ww, histf[k]);
            ss = __fadd_rn(ss, __fmul_rn(histf[k], centers[k]));
            w1a[k] = ww;
            s1a[k] = ss;
        }
    }
    __syncthreads();
    float v = -1.0f;
    int ti = 256;
    if (t < 255) {                                 // parallel variance evals
        float m1 = __fdiv_rn(s1a[t], fmaxf(w1a[t], 1.0f));
        float m2 = __fdiv_rn(s2a[t + 1], fmaxf(w2a[t + 1], 1.0f));
        float d  = __fsub_rn(m1, m2);
        v  = __fmul_rn(__fmul_rn(w1a[t], w2a[t + 1]), __fmul_rn(d, d));
        ti = t;
    }
    for (int off = 32; off > 0; off >>= 1) {       // first-max argmax reduce
        float ov = __shfl_xor(v, off, 64);
        int oi = __shfl_xor(ti, off, 64);
        if (ov > v || (ov == v && oi < ti)) { v = ov; ti = oi; }
    }
    if (lane == 0) { rbv[w] = v; rbi[w] = ti; }
    __syncthreads();
    if (t == 0) {
        float bv = rbv[0]; int bi = rbi[0];
        for (int k = 1; k < 4; ++k)
            if (rbv[k] > bv || (rbv[k] == bv && rbi[k] < bi)) {
                bv = rbv[k]; bi = rbi[k];
            }
        sthresh = centers[bi];
    }
    __syncthreads();
    const float thr = sthresh;

    const int ma = lane / 3,         qa = lane % 3;
    const int mb = (64 + lane) / 3,  qb = (64 + lane) % 3;
    const int mc = (128 + lane) / 3, qc = (128 + lane) % 3;
#pragma unroll
    for (int r = 0; r < 8; ++r) {
        const int gbase = gw * 512 + r * 64;
        unsigned u = (gg[r].x > thr ? 1u : 0u) |
                     (gg[r].y > thr ? 0x100u : 0u) |
                     (gg[r].z > thr ? 0x10000u : 0u) |
                     (gg[r].w > thr ? 0x1000000u : 0u);
        const size_t rb = 3 * (size_t)gbase;
#pragma unroll
        for (int k = 0; k < 3; ++k) {
            int m = (k == 0) ? ma : (k == 1) ? mb : mc;
            int q = (k == 0) ? qa : (k == 1) ? qb : qc;
            unsigned x = (unsigned)__builtin_amdgcn_ds_bpermute(4 * m, (int)u);
            float h0 = (x & 0xffu)       ? 1.0f : 0.0f;
            float h1 = (x & 0xff00u)     ? 1.0f : 0.0f;
            float h2 = (x & 0xff0000u)   ? 1.0f : 0.0f;
            float h3 = (x & 0xff000000u) ? 1.0f : 0.0f;
            nfloat4 o;
            o.x = (q == 0) ? h0 : (q == 1) ? h1 : h2;
            o.y = (q == 0) ? h0 : (q == 1) ? h1 : h3;
            o.z = (q == 0) ? h0 : (q == 1) ? h2 : h3;
            o.w = (q == 0) ? h1 : (q == 1) ? h2 : h3;
            __builtin_nontemporal_store(o, &out4[rb + 64 * k + lane]);
        }
    }
}

// =============== R5 3-kernel pipeline (proven 237.8 us) — fallback ==========

__device__ __forceinline__ void reduce_pairs(const unsigned* __restrict__ wsu,
                                             int npairs, int t,
                                             unsigned& mn, unsigned& mx,
                                             unsigned* rmn, unsigned* rmx) {
    mn = 0xFFFFFFFFu; mx = 0u;
    for (int i = t; i < npairs; i += 256) {
        mn = min(mn, wsu[SCRATCH_OFF + 2 * i]);
        mx = max(mx, wsu[SCRATCH_OFF + 2 * i + 1]);
    }
    for (int off = 32; off > 0; off >>= 1) {
        mn = min(mn, (unsigned)__shfl_xor((int)mn, off, 64));
        mx = max(mx, (unsigned)__shfl_xor((int)mx, off, 64));
    }
    const int w = t >> 6;
    if ((t & 63) == 0) { rmn[w] = mn; rmx[w] = mx; }
    __syncthreads();
    mn = min(min(rmn[0], rmn[1]), min(rmn[2], rmn[3]));
    mx = max(max(rmx[0], rmx[1]), max(rmx[2], rmx[3]));
}

__global__ void __launch_bounds__(256)
gray_minmax_lds(const float* __restrict__ in, float* __restrict__ gray,
                unsigned* __restrict__ wsu, int npix4) {
    __shared__ float4 sb[4][2][192];
    __shared__ unsigned smn[4], smx[4];
    const float4* __restrict__ in4 = (const float4*)in;
    float4* __restrict__ gray4 = (float4*)gray;
    const int lane = threadIdx.x & 63;
    const int w = threadIdx.x >> 6;
    const int gw = blockIdx.x * 4 + w;
    const size_t base = (size_t)gw * 768;
    unsigned mn = 0xFFFFFFFFu, mx = 0u;

    if (blockIdx.x == 0) wsu[HIST_OFF + threadIdx.x] = 0u;

    float4 a0 = in4[base + lane];
    float4 a1 = in4[base + 64 + lane];
    float4 a2 = in4[base + 128 + lane];
    __builtin_amdgcn_sched_barrier(0);
    sb[w][0][lane]       = a0;
    sb[w][0][64 + lane]  = a1;
    sb[w][0][128 + lane] = a2;
    a0 = in4[base + 192 + lane];
    a1 = in4[base + 256 + lane];
    a2 = in4[base + 320 + lane];
    __builtin_amdgcn_sched_barrier(0);

#pragma unroll
    for (int t = 0; t < 4; ++t) {
        const int cb = t & 1;
        float4 c0 = sb[w][cb][3 * lane + 0];
        float4 c1 = sb[w][cb][3 * lane + 1];
        float4 c2 = sb[w][cb][3 * lane + 2];
        float g0 = gray1(c0.x, c0.y, c0.z);
        float g1 = gray1(c0.w, c1.x, c1.y);
        float g2 = gray1(c1.z, c1.w, c2.x);
        float g3 = gray1(c2.y, c2.z, c2.w);
        gray4[(size_t)gw * 256 + t * 64 + lane] = make_float4(g0, g1, g2, g3);
        unsigned k0 = fkey(g0), k1 = fkey(g1), k2 = fkey(g2), k3 = fkey(g3);
        mn = min(mn, min(min(k0, k1), min(k2, k3)));
        mx = max(mx, max(max(k0, k1), max(k2, k3)));
        if (t < 3) {
            sb[w][cb ^ 1][lane]       = a0;
            sb[w][cb ^ 1][64 + lane]  = a1;
            sb[w][cb ^ 1][128 + lane] = a2;
            if (t < 2) {
                a0 = in4[base + (size_t)(t + 2) * 192 + lane];
                a1 = in4[base + (size_t)(t + 2) * 192 + 64 + lane];
                a2 = in4[base + (size_t)(t + 2) * 192 + 128 + lane];
            }
            __builtin_amdgcn_sched_barrier(0);
        }
    }
    for (int off = 32; off > 0; off >>= 1) {
        mn = min(mn, (unsigned)__shfl_xor((int)mn, off, 64));
        mx = max(mx, (unsigned)__shfl_xor((int)mx, off, 64));
    }
    if (lane == 0) { smn[w] = mn; smx[w] = mx; }
    __syncthreads();
    if (threadIdx.x == 0) {
        mn = min(min(smn[0], smn[1]), min(smn[2], smn[3]));
        mx = max(max(smx[0], smx[1]), max(smx[2], smx[3]));
        wsu[SCRATCH_OFF + 2 * blockIdx.x]     = mn;
        wsu[SCRATCH_OFF + 2 * blockIdx.x + 1] = mx;
    }
}

__global__ void __launch_bounds__(256)
hist_fused(const float* __restrict__ gray, unsigned* __restrict__ wsu,
           int npairs, int npix4) {
    __shared__ float eds[257];
    __shared__ unsigned lh[256];
    __shared__ unsigned rmn[4], rmx[4];
    const int t = threadIdx.x;
    unsigned mn, mx;
    reduce_pairs(wsu, npairs, t, mn, mx, rmn, rmx);
    const float vmin = keyf(mn);
    const float vmax = keyf(mx);
    const float delta = __fdiv_rn(__fsub_rn(vmax, vmin), 256.0f);
    const float invd = (delta > 0.0f) ? __fdiv_rn(1.0f, delta) : 0.0f;
    eds[t] = __fadd_rn(vmin, __fmul_rn((float)t, delta));
    if (t == 0) eds[256] = vmax;
    lh[t] = 0u;
    __syncthreads();

    const int stride = gridDim.x * 256;
    const int base = blockIdx.x * 256 + t;
    float4 g[8];
#pragma unroll
    for (int j = 0; j < 8; ++j) g[j] = ((const float4*)gray)[base + j * stride];
#pragma unroll
    for (int j = 0; j < 8; ++j)
        bin4(g[j].x, g[j].y, g[j].z, g[j].w, eds, vmin, invd, lh);
    __syncthreads();
    if (lh[t] != 0u) atomicAdd(&wsu[HIST_OFF + t], lh[t]);
}

__global__ void __launch_bounds__(256)
binarize_fused(const float* __restrict__ gray, const unsigned* __restrict__ wsu,
               float* __restrict__ out, int npairs, int npix4) {
    __shared__ float eds[257];
    __shared__ float histf[256], centers[256];
    __shared__ float w1a[256], s1a[256], w2a[256], s2a[256];
    __shared__ unsigned rmn[4], rmx[4];
    __shared__ float rbv[4];
    __shared__ int rbi[4];
    __shared__ float sthresh;
    const int t = threadIdx.x;
    const int lane = t & 63;
    const int w = t >> 6;

    unsigned mn, mx;
    reduce_pairs(wsu, npairs, t, mn, mx, rmn, rmx);
    const float vmin = keyf(mn);
    const float vmax = keyf(mx);
    const float delta = __fdiv_rn(__fsub_rn(vmax, vmin), 256.0f);
    eds[t] = __fadd_rn(vmin, __fmul_rn((float)t, delta));
    if (t == 0) eds[256] = vmax;
    histf[t] = (float)wsu[HIST_OFF + t];
    __syncthreads();
    centers[t] = __fmul_rn(__fadd_rn(eds[t], eds[t + 1]), 0.5f);
    __syncthreads();
    if (t == 0) {
        float ww = 0.0f, ss = 0.0f;
        for (int k = 255; k >= 0; --k) {
            ww = __fadd_rn(ww, histf[k]);
            ss = __fadd_rn(ss, __fmul_rn(histf[k], centers[k]));
            w2a[k] = ww;
            s2a[k] = ss;
        }
        ww = 0.0f; ss = 0.0f;
        for (int k = 0; k < 255; ++k) {
            ww = __fadd_rn(ww, histf[k]);
            ss = __fadd_rn(ss, __fmul_rn(histf[k], centers[k]));
            w1a[k] = ww;
            s1a[k] = ss;
        }
    }
    __syncthreads();
    float v = -1.0f;
    int ti = 256;
    if (t < 255) {
        float m1 = __fdiv_rn(s1a[t], fmaxf(w1a[t], 1.0f));
        float m2 = __fdiv_rn(s2a[t + 1], fmaxf(w2a[t + 1], 1.0f));
        float d  = __fsub_rn(m1, m2);
        v  = __fmul_rn(__fmul_rn(w1a[t], w2a[t + 1]), __fmul_rn(d, d));
        ti = t;
    }
    for (int off = 32; off > 0; off >>= 1) {
        float ov = __shfl_xor(v, off, 64);
        int oi = __shfl_xor(ti, off, 64);
        if (ov > v || (ov == v && oi < ti)) { v = ov; ti = oi; }
    }
    if (lane == 0) { rbv[w] = v; rbi[w] = ti; }
    __syncthreads();
    if (t == 0) {
        float bv = rbv[0]; int bi = rbi[0];
        for (int k = 1; k < 4; ++k)
            if (rbv[k] > bv || (rbv[k] == bv && rbi[k] < bi)) {
                bv = rbv[k]; bi = rbi[k];
            }
        sthresh = centers[bi];
    }
    __syncthreads();
    const float thr = sthresh;

    const nfloat4* gray4 = (const nfloat4*)gray;
    nfloat4* out4 = (nfloat4*)out;
    const int gw = blockIdx.x * 4 + w;
    const int ma = lane / 3,         qa = lane % 3;
    const int mb = (64 + lane) / 3,  qb = (64 + lane) % 3;
    const int mc = (128 + lane) / 3, qc = (128 + lane) % 3;
#pragma unroll
    for (int r = 0; r < 8; ++r) {
        const int gbase = gw * 512 + r * 64;
        nfloat4 gg = gray4[gbase + lane];
        unsigned u = (gg.x > thr ? 1u : 0u) |
                     (gg.y > thr ? 0x100u : 0u) |
                     (gg.z > thr ? 0x10000u : 0u) |
                     (gg.w > thr ? 0x1000000u : 0u);
        const size_t rb = 3 * (size_t)gbase;
#pragma unroll
        for (int k = 0; k < 3; ++k) {
            int m = (k == 0) ? ma : (k == 1) ? mb : mc;
            int q = (k == 0) ? qa : (k == 1) ? qb : qc;
            unsigned x = (unsigned)__builtin_amdgcn_ds_bpermute(4 * m, (int)u);
            float h0 = (x & 0xffu)       ? 1.0f : 0.0f;
            float h1 = (x & 0xff00u)     ? 1.0f : 0.0f;
            float h2 = (x & 0xff0000u)   ? 1.0f : 0.0f;
            float h3 = (x & 0xff000000u) ? 1.0f : 0.0f;
            nfloat4 o;
            o.x = (q == 0) ? h0 : (q == 1) ? h1 : h2;
            o.y = (q == 0) ? h0 : (q == 1) ? h1 : h3;
            o.z = (q == 0) ? h0 : (q == 1) ? h2 : h3;
            o.w = (q == 0) ? h1 : (q == 1) ? h2 : h3;
            __builtin_nontemporal_store(o, &out4[rb + 64 * k + lane]);
        }
    }
}

// =============== generic multi-kernel fallback (any size) ===================

__global__ void init_kernel(unsigned* __restrict__ wsu) {
    int i = threadIdx.x;
    if (i < 256) wsu[HIST_OFF + i] = 0u;
    if (i == 0) { wsu[0] = 0xFFFFFFFFu; wsu[1] = 0u; }
}

__global__ void __launch_bounds__(256)
gray_minmax_generic(const float* __restrict__ in, float* __restrict__ gray,
                    unsigned* __restrict__ wsu, int npix4) {
    __shared__ unsigned smn[4], smx[4];
    const float4* in4 = (const float4*)in;
    const int stride = gridDim.x * blockDim.x;
    unsigned mn = 0xFFFFFFFFu, mx = 0u;
    for (int t = blockIdx.x * blockDim.x + threadIdx.x; t < npix4; t += stride) {
        const float4* p = in4 + (size_t)t * 3;
        float4 c0 = p[0], c1 = p[1], c2 = p[2];
        float g0 = gray1(c0.x, c0.y, c0.z);
        float g1 = gray1(c0.w, c1.x, c1.y);
        float g2 = gray1(c1.z, c1.w, c2.x);
        float g3 = gray1(c2.y, c2.z, c2.w);
        if (gray) ((float4*)gray)[t] = make_float4(g0, g1, g2, g3);
        unsigned k0 = fkey(g0), k1 = fkey(g1), k2 = fkey(g2), k3 = fkey(g3);
        mn = min(mn, min(min(k0, k1), min(k2, k3)));
        mx = max(mx, max(max(k0, k1), max(k2, k3)));
    }
    for (int off = 32; off > 0; off >>= 1) {
        mn = min(mn, (unsigned)__shfl_xor((int)mn, off, 64));
        mx = max(mx, (unsigned)__shfl_xor((int)mx, off, 64));
    }
    int wave = threadIdx.x >> 6;
    if ((threadIdx.x & 63) == 0) { smn[wave] = mn; smx[wave] = mx; }
    __syncthreads();
    if (threadIdx.x == 0) {
        mn = min(min(smn[0], smn[1]), min(smn[2], smn[3]));
        mx = max(max(smx[0], smx[1]), max(smx[2], smx[3]));
        atomicMin(&wsu[0], mn);
        atomicMax(&wsu[1], mx);
    }
}

__global__ void edges_kernel(unsigned* __restrict__ wsu,
                             float* __restrict__ wsf, int nblk) {
    const int i = threadIdx.x;
    unsigned mn = wsu[0], mx = wsu[1];
    const float vmin = keyf(mn);
    const float vmax = keyf(mx);
    const float delta = __fdiv_rn(__fsub_rn(vmax, vmin), 256.0f);
    wsf[EDGES_OFF + i] = __fadd_rn(vmin, __fmul_rn((float)i, delta));
    if (i == 0) {
        wsf[EDGES_OFF + 256] = vmax;
        wsf[VMIN_OFF]  = vmin;
        wsf[DELTA_OFF] = delta;
        wsf[INVD_OFF]  = (delta > 0.0f) ? __fdiv_rn(1.0f, delta) : 0.0f;
    }
}

__global__ void __launch_bounds__(256)
hist_kernel(const float* __restrict__ gray, const float* __restrict__ in,
            const float* __restrict__ wsf, unsigned* __restrict__ wsu,
            int npix4) {
    __shared__ float eds[257];
    __shared__ unsigned lh[256];
    for (int i = threadIdx.x; i < 257; i += blockDim.x)
        eds[i] = wsf[EDGES_OFF + i];
    if (threadIdx.x < 256) lh[threadIdx.x] = 0u;
    __syncthreads();
    const float vmin = eds[0];
    const float invd = wsf[INVD_OFF];
    const int stride = gridDim.x * blockDim.x;
    const int base = blockIdx.x * blockDim.x + threadIdx.x;
    for (int t = base; t < npix4; t += stride) {
        float4 g4;
        if (gray) g4 = ((const float4*)gray)[t];
        else {
            const float4* p = (const float4*)in + (size_t)t * 3;
            float4 c0 = p[0], c1 = p[1], c2 = p[2];
            g4 = make_float4(gray1(c0.x, c0.y, c0.z), gray1(c0.w, c1.x, c1.y),
                             gray1(c1.z, c1.w, c2.x), gray1(c2.y, c2.z, c2.w));
        }
        bin4(g4.x, g4.y, g4.z, g4.w, eds, vmin, invd, lh);
    }
    __syncthreads();
    if (threadIdx.x < 256 && lh[threadIdx.x] != 0u)
        atomicAdd(&wsu[HIST_OFF + threadIdx.x], lh[threadIdx.x]);
}

__global__ void otsu_kernel(const unsigned* __restrict__ wsu,
                            float* __restrict__ wsf) {
    __shared__ float histf[256];
    __shared__ float centers[256];
    __shared__ float w2a[256];
    __shared__ float s2a[256];
    int i = threadIdx.x;
    float e0 = wsf[EDGES_OFF + i];
    float e1 = wsf[EDGES_OFF + i + 1];
    centers[i] = __fmul_rn(__fadd_rn(e0, e1), 0.5f);
    histf[i] = (float)wsu[HIST_OFF + i];
    __syncthreads();
    if (i == 0) {
        float w = 0.0f, s = 0.0f;
        for (int t = 255; t >= 0; --t) {
            w = __fadd_rn(w, histf[t]);
            s = __fadd_rn(s, __fmul_rn(histf[t], centers[t]));
            w2a[t] = w;
            s2a[t] = s;
        }
        float w1 = 0.0f, s1 = 0.0f, best = -1.0f;
        int bidx = 0;
        for (int t = 0; t < 255; ++t) {
            w1 = __fadd_rn(w1, histf[t]);
            s1 = __fadd_rn(s1, __fmul_rn(histf[t], centers[t]));
            float m1 = __fdiv_rn(s1, fmaxf(w1, 1.0f));
            float m2 = __fdiv_rn(s2a[t + 1], fmaxf(w2a[t + 1], 1.0f));
            float d  = __fsub_rn(m1, m2);
            float v  = __fmul_rn(__fmul_rn(w1, w2a[t + 1]), __fmul_rn(d, d));
            if (v > best) { best = v; bidx = t; }
        }
        wsf[THRESH_OFF] = centers[bidx];
    }
}

__global__ void __launch_bounds__(256)
binarize_generic(const float* __restrict__ gray, const float* __restrict__ in,
                 const float* __restrict__ wsf, float* __restrict__ out,
                 int npix4) {
    const float thr = wsf[THRESH_OFF];
    const int stride = gridDim.x * blockDim.x;
    nfloat4* out4 = (nfloat4*)out;
    for (int t = blockIdx.x * blockDim.x + threadIdx.x; t < npix4; t += stride) {
        float4 g4;
        if (gray) g4 = ((const float4*)gray)[t];
        else {
            const float4* p = (const float4*)in + (size_t)t * 3;
            float4 c0 = p[0], c1 = p[1], c2 = p[2];
            g4 = make_float4(gray1(c0.x, c0.y, c0.z), gray1(c0.w, c1.x, c1.y),
                             gray1(c1.z, c1.w, c2.x), gray1(c2.y, c2.z, c2.w));
        }
        float b0 = (g4.x > thr) ? 1.0f : 0.0f;
        float b1 = (g4.y > thr) ? 1.0f : 0.0f;
        float b2 = (g4.z > thr) ? 1.0f : 0.0f;
        float b3 = (g4.w > thr) ? 1.0f : 0.0f;
        nfloat4* o = out4 + (size_t)t * 3;
        o[0] = (nfloat4){b0, b0, b0, b1};
        o[1] = (nfloat4){b1, b1, b2, b2};
        o[2] = (nfloat4){b2, b3, b3, b3};
    }
}

static void launch_generic(const float* in, float* out, unsigned* wsu,
                           float* wsf, float* gray, int npix4,
                           hipStream_t stream) {
    hipLaunchKernelGGL(init_kernel, dim3(1), dim3(256), 0, stream, wsu);
    hipLaunchKernelGGL(gray_minmax_generic, dim3(2048), dim3(256), 0,
                       stream, in, gray, wsu, npix4);
    hipLaunchKernelGGL(edges_kernel, dim3(1), dim3(256), 0, stream, wsu, wsf,
                       0);
    hipLaunchKernelGGL(hist_kernel, dim3(1024), dim3(256), 0, stream,
                       gray, in, wsf, wsu, npix4);
    hipLaunchKernelGGL(otsu_kernel, dim3(1), dim3(256), 0, stream, wsu, wsf);
    hipLaunchKernelGGL(binarize_generic, dim3(2048), dim3(256), 0, stream,
                       gray, in, wsf, out, npix4);
}

extern "C" void kernel_launch(void* const* d_in, const int* in_sizes, int n_in,
                              void* d_out, int out_size, void* d_ws,
                              size_t ws_size, hipStream_t stream) {
    const float* in = (const float*)d_in[0];
    float* out = (float*)d_out;
    int npix  = out_size / 3;
    int npix4 = npix / 4;
    unsigned* wsu = (unsigned*)d_ws;
    float* wsf = (float*)d_ws;
    size_t need = GRAY_BYTE_OFF + (size_t)npix * sizeof(float);
    float* gray = (ws_size >= need)
                      ? (float*)((char*)d_ws + GRAY_BYTE_OFF)
                      : nullptr;

    // co-residency capacity for the fused kernel (host-only, cached)
    static int capacity = -2;
    if (capacity == -2) {
        capacity = -1;
        int dev = 0, nb = 0;
        hipDeviceProp_t prop;
        if (hipGetDevice(&dev) == hipSuccess &&
            hipGetDeviceProperties(&prop, dev) == hipSuccess &&
            hipOccupancyMaxActiveBlocksPerMultiprocessor(
                &nb, (const void*)fused_all, 256, 0) == hipSuccess)
            capacity = nb * prop.multiProcessorCount;
    }

    const int NB = npix4 / 2048;
    const bool fused_ok = (npix4 % 2048 == 0) && NB >= 1 && capacity >= NB &&
                          ws_size >= (size_t)(SCRATCH_OFF + 2 * NB) * 4;
    if (fused_ok) {
        // zero hist + barrier counters (poisoned between iterations)
        hipMemsetAsync(wsu, 0, 4096, stream);
        hipLaunchKernelGGL(fused_all, dim3(NB), dim3(256), 0, stream,
                           in, out, wsu, NB);
        return;
    }
    const bool fast = gray && (npix4 % 2048 == 0);
    if (fast) {
        const int npairs = npix4 / 1024;
        const int nb2 = npix4 / 2048;
        hipLaunchKernelGGL(gray_minmax_lds, dim3(npairs), dim3(256), 0,
                           stream, in, gray, wsu, npix4);
        hipLaunchKernelGGL(hist_fused, dim3(nb2), dim3(256), 0, stream,
                           gray, wsu, npairs, npix4);
        hipLaunchKernelGGL(binarize_fused, dim3(nb2), dim3(256), 0, stream,
                           gray, wsu, out, npairs, npix4);
    } else {
        launch_generic(in, out, wsu, wsf, gray, npix4, stream);
    }
}